// Round 20
// baseline (657.035 us; speedup 1.0000x reference)
//
#include <hip/hip_runtime.h>
#include <math.h>

#define T_ 256
#define B_ 8
#define S_ 512
#define E_ 1024
#define FF_ 4096
#define V_ 32000
#define LN_EPSF 1e-5f

typedef __attribute__((ext_vector_type(8))) short short8;
typedef __attribute__((ext_vector_type(4))) float f32x4;
typedef unsigned short us;

// ---------------- block reduction helpers -----------------------------------
__device__ __forceinline__ float blkSum(float v, float* sh) {
#pragma unroll
  for (int o = 32; o > 0; o >>= 1) v += __shfl_down(v, o, 64);
  if ((threadIdx.x & 63) == 0) sh[threadIdx.x >> 6] = v;
  __syncthreads();
  float r = sh[0] + sh[1] + sh[2] + sh[3];
  __syncthreads();
  return r;
}
__device__ __forceinline__ float blkMax(float v, float* sh) {
#pragma unroll
  for (int o = 32; o > 0; o >>= 1) v = fmaxf(v, __shfl_down(v, o, 64));
  if ((threadIdx.x & 63) == 0) sh[threadIdx.x >> 6] = v;
  __syncthreads();
  float r = fmaxf(fmaxf(sh[0], sh[1]), fmaxf(sh[2], sh[3]));
  __syncthreads();
  return r;
}
__device__ __forceinline__ float blkSum16(float v, float* sh) {
#pragma unroll
  for (int o = 32; o > 0; o >>= 1) v += __shfl_down(v, o, 64);
  if ((threadIdx.x & 63) == 0) sh[threadIdx.x >> 6] = v;
  __syncthreads();
  float r = 0.f;
#pragma unroll
  for (int i = 0; i < 16; ++i) r += sh[i];
  __syncthreads();
  return r;
}
__device__ __forceinline__ float blkMax16(float v, float* sh) {
#pragma unroll
  for (int o = 32; o > 0; o >>= 1) v = fmaxf(v, __shfl_down(v, o, 64));
  if ((threadIdx.x & 63) == 0) sh[threadIdx.x >> 6] = v;
  __syncthreads();
  float r = -INFINITY;
#pragma unroll
  for (int i = 0; i < 16; ++i) r = fmaxf(r, sh[i]);
  __syncthreads();
  return r;
}

// ---------------- f32 -> bf16 via HW cvt_pk (RNE) ---------------------------
__device__ __forceinline__ unsigned pkbf(float a, float b) {
  unsigned r;
  asm("v_cvt_pk_bf16_f32 %0, %1, %2" : "=v"(r) : "v"(a), "v"(b));
  return r;
}
__device__ __forceinline__ us bf16o(float a) {
  return (us)(pkbf(a, a) & 0xffffu);
}
__device__ __forceinline__ float bf2f(us u) {
  return __uint_as_float(((unsigned)u) << 16);
}

// ---------------- async global->LDS, 16B per lane ---------------------------
__device__ __forceinline__ void gl16(const us* g, us* l) {
  __builtin_amdgcn_global_load_lds(
      (const __attribute__((address_space(1))) void*)g,
      (__attribute__((address_space(3))) void*)l, 16, 0, 0);
}

// LDS XOR swizzle for the reg-staged nt kernel only (store+read, same xor)
__device__ __forceinline__ int swz(int idx) {
  return idx ^ (((idx >> 10) & 3) << 4);
}

// bijective XCD swizzle (m204): row-tile fastest within each XCD chunk
__device__ __forceinline__ void tile_map(int& rowT, int& colT) {
  const unsigned nwg = gridDim.x * gridDim.y;
  const unsigned lin = blockIdx.y * gridDim.x + blockIdx.x;
  const unsigned nq = nwg >> 3, rr = nwg & 7;
  const unsigned xcd = lin & 7, idx = lin >> 3;
  const unsigned s =
      (xcd < rr ? xcd * (nq + 1) : rr * (nq + 1) + (xcd - rr) * nq) + idx;
  rowT = s % gridDim.x;
  colT = s / gridDim.x;
}

// ---------------- cvt: fp32 -> packed bf16 (single big buffer) --------------
__global__ __launch_bounds__(256) void cvt_bf16(
    const float* __restrict__ in, us* __restrict__ o, int n4)
{
  int i = blockIdx.x * 256 + threadIdx.x;
  if (i < n4) {
    float4 f = ((const float4*)in)[i];
    ((uint2*)o)[i] = make_uint2(pkbf(f.x, f.y), pkbf(f.z, f.w));
  }
}

// ---------------- merged cvt of 6 tensors in one dispatch -------------------
__global__ __launch_bounds__(256) void cvt_all(
    const float* __restrict__ s0, us* __restrict__ d0,   // outs    524288
    const float* __restrict__ s1, us* __restrict__ d1,   // mem    1048576
    const float* __restrict__ s2, us* __restrict__ d2,   // in_w    786432
    const float* __restrict__ s3, us* __restrict__ d3,   // ow      262144
    const float* __restrict__ s4, us* __restrict__ d4,   // fc1    1048576
    const float* __restrict__ s5, us* __restrict__ d5)   // fc2    1048576
{
  int j = blockIdx.x * 256 + threadIdx.x;
  const float* s; us* d;
  if (j < 524288) { s = s0; d = d0; }
  else { j -= 524288; if (j < 1048576) { s = s1; d = d1; }
  else { j -= 1048576; if (j < 786432) { s = s2; d = d2; }
  else { j -= 786432; if (j < 262144) { s = s3; d = d3; }
  else { j -= 262144; if (j < 1048576) { s = s4; d = d4; }
  else { j -= 1048576; if (j >= 1048576) return; s = s5; d = d5; } } } } }
  float4 f = ((const float4*)s)[j];
  ((uint2*)d)[j] = make_uint2(pkbf(f.x, f.y), pkbf(f.z, f.w));
}

// ======== 256x256-tile bf16 GEMM: BK=32, 2 buf, 2 phases, 64 KB LDS =========
// Same phase discipline as the BK=64 version but 64 KB LDS -> 2 blocks/CU
// (16 waves/CU at 92 VGPR): cross-block TLP absorbs the barrier drains.
template<int CBF>
__global__ __launch_bounds__(512) void gemm_8p32(
    const us* __restrict__ A, const us* __restrict__ Bm,
    const float* __restrict__ bias, void* __restrict__ Cv,
    int K, int lda, int ldb, int ldc, float scale, int relu)
{
  __shared__ us sA[2][8192], sB[2][8192];   // 64 KB
  int rowT, colT;
  tile_map(rowT, colT);
  const int row0 = rowT * 256, col0 = colT * 256;
  const us* Ap = A + (long)row0 * lda;
  const us* Bp = Bm + (long)col0 * ldb;

  const int lane = threadIdx.x & 63, wid = threadIdx.x >> 6;  // 8 waves
  const int wr = wid >> 2, wc = wid & 3;                      // 2x4 wave grid
  const int lr = lane & 15, kb = lane >> 4;

  // 16 chunks/operand per K-tile(32): chunk c = wid*2+i: kg=c&3, rq=c>>2
  long asrc[2], bsrc[2];
  int dst[2];
#pragma unroll
  for (int i = 0; i < 2; ++i) {
    int c = wid * 2 + i;
    int kg = c & 3, rq = c >> 2;
    asrc[i] = (long)(rq * 64 + lane) * lda + kg * 8;
    bsrc[i] = (long)(rq * 64 + lane) * ldb + kg * 8;
    dst[i] = kg * 2048 + rq * 512;   // [kg(4)][256][8]; HW adds lane*16B
  }

  f32x4 acc[8][4];
#pragma unroll
  for (int j = 0; j < 8; ++j)
#pragma unroll
    for (int ni = 0; ni < 4; ++ni) {
      f32x4 z = {0.f, 0.f, 0.f, 0.f};
      acc[j][ni] = z;
    }

  const int nt = K >> 5;
#pragma unroll
  for (int i = 0; i < 2; ++i) gl16(Bp + bsrc[i], &sB[0][dst[i]]);
#pragma unroll
  for (int i = 0; i < 2; ++i) gl16(Ap + asrc[i], &sA[0][dst[i]]);
  asm volatile("s_waitcnt vmcnt(0)" ::: "memory");
  __builtin_amdgcn_s_barrier();

  for (int t = 0; t < nt; ++t) {
    const int buf = t & 1, nbuf = buf ^ 1;
    const long kN = (long)(t + 1) << 5;
    const bool pf = (t + 1) < nt;
    short8 bfr[4], af[4];

    // ---- phase 0: B frags + A rows [0,64); prefetch next K-tile ----
#pragma unroll
    for (int ni = 0; ni < 4; ++ni)
      bfr[ni] = *(const short8*)&sB[buf][kb * 2048 + (wc * 64 + ni * 16 + lr) * 8];
#pragma unroll
    for (int mi = 0; mi < 4; ++mi)
      af[mi] = *(const short8*)&sA[buf][kb * 2048 + (wr * 128 + mi * 16 + lr) * 8];
    if (pf) {
#pragma unroll
      for (int i = 0; i < 2; ++i) gl16(Bp + bsrc[i] + kN, &sB[nbuf][dst[i]]);
#pragma unroll
      for (int i = 0; i < 2; ++i) gl16(Ap + asrc[i] + kN, &sA[nbuf][dst[i]]);
    }
    __builtin_amdgcn_s_barrier();
    asm volatile("s_waitcnt lgkmcnt(0)" ::: "memory");
    __builtin_amdgcn_sched_barrier(0);
    __builtin_amdgcn_s_setprio(1);
#pragma unroll
    for (int mi = 0; mi < 4; ++mi)
#pragma unroll
      for (int ni = 0; ni < 4; ++ni)
        acc[mi][ni] = __builtin_amdgcn_mfma_f32_16x16x32_bf16(
            af[mi], bfr[ni], acc[mi][ni], 0, 0, 0);
    __builtin_amdgcn_s_setprio(0);
    __builtin_amdgcn_s_barrier();

    // ---- phase 1: A rows [64,128); closing barrier = next-tile-ready ----
#pragma unroll
    for (int mi = 0; mi < 4; ++mi)
      af[mi] = *(const short8*)&sA[buf][kb * 2048 + (wr * 128 + 64 + mi * 16 + lr) * 8];
    __builtin_amdgcn_s_barrier();
    asm volatile("s_waitcnt lgkmcnt(0)" ::: "memory");
    __builtin_amdgcn_sched_barrier(0);
    __builtin_amdgcn_s_setprio(1);
#pragma unroll
    for (int mi = 0; mi < 4; ++mi)
#pragma unroll
      for (int ni = 0; ni < 4; ++ni)
        acc[4 + mi][ni] = __builtin_amdgcn_mfma_f32_16x16x32_bf16(
            af[mi], bfr[ni], acc[4 + mi][ni], 0, 0, 0);
    __builtin_amdgcn_s_setprio(0);
    asm volatile("s_waitcnt vmcnt(0)" ::: "memory");   // next tile landed
    __builtin_amdgcn_s_barrier();
  }

  // epilogue: C/D layout col=lane&15, row=(lane>>4)*4+reg
#pragma unroll
  for (int j = 0; j < 8; ++j)
#pragma unroll
    for (int ni = 0; ni < 4; ++ni) {
      int col = col0 + wc * 64 + ni * 16 + lr;
      float bv = bias ? bias[col] : 0.0f;
#pragma unroll
      for (int r = 0; r < 4; ++r) {
        int row = row0 + wr * 128 + (j >> 2) * 64 + (j & 3) * 16 + kb * 4 + r;
        float vv = (acc[j][ni][r] + bv) * scale;
        if (relu) vv = fmaxf(vv, 0.0f);
        if constexpr (CBF)
          ((us*)Cv)[(long)row * ldc + col] = bf16o(vv);
        else
          ((float*)Cv)[(long)row * ldc + col] = vv;
      }
    }
}

// ---------------- 128x128 bf16 GEMM, gl_lds, BK=32, 3-buf counted vmcnt -----
// z decomposes as (zb = z % zdiv, zs = z / zdiv): batch offsets (aB,bB,cB)
// and split-K offsets (aK,bK,cK) in elements.
template<int CBF>
__global__ __launch_bounds__(256) void gemm_gl(
    const us* __restrict__ A, const us* __restrict__ Bm,
    const float* __restrict__ bias, const float* __restrict__ sbias,
    void* __restrict__ Cv, int K, int lda, int ldb, int ldc, int zdiv,
    long aB, long bB, long cB, long aK, long bK, long cK,
    float scale, int relu)
{
  __shared__ us sA[3][4096], sB[3][4096];   // 48 KB -> 3 blocks/CU
  int rowT, colT;
  tile_map(rowT, colT);
  const int bz = blockIdx.z;
  const int zb = bz % zdiv, zs = bz / zdiv;
  const int row0 = rowT * 128, col0 = colT * 128;
  const us* Ap = A + (long)zb * aB + (long)zs * aK + (long)row0 * lda;
  const us* Bp = Bm + (long)zb * bB + (long)zs * bK + (long)col0 * ldb;
  const float sb = sbias ? sbias[zb] : 0.0f;

  const int lane = threadIdx.x & 63, wid = threadIdx.x >> 6;
  const int wr = wid >> 1, wc = wid & 1;
  const int lr = lane & 15, kb = lane >> 4;

  const int r1 = threadIdx.x & 127, q1 = threadIdx.x >> 7;
  const long a1 = (long)r1 * lda + q1 * 8, a2 = a1 + 16;
  const long b1 = (long)r1 * ldb + q1 * 8, b2 = b1 + 16;
  const int dof1 = wid * 512, dof2 = 2048 + wid * 512;

  f32x4 acc[4][4];
#pragma unroll
  for (int mi = 0; mi < 4; ++mi)
#pragma unroll
    for (int ni = 0; ni < 4; ++ni) {
      f32x4 z = {0.f, 0.f, 0.f, 0.f};
      acc[mi][ni] = z;
    }

  auto stage = [&](int buf, long k0) {
    gl16(Ap + a1 + k0, &sA[buf][dof1]);
    gl16(Ap + a2 + k0, &sA[buf][dof2]);
    gl16(Bp + b1 + k0, &sB[buf][dof1]);
    gl16(Bp + b2 + k0, &sB[buf][dof2]);
  };
  auto compute = [&](int buf) {
    short8 af[4], bfr[4];
#pragma unroll
    for (int mi = 0; mi < 4; ++mi)
      af[mi] = *(const short8*)&sA[buf][kb * 1024 + (wr * 64 + mi * 16 + lr) * 8];
#pragma unroll
    for (int ni = 0; ni < 4; ++ni)
      bfr[ni] = *(const short8*)&sB[buf][kb * 1024 + (wc * 64 + ni * 16 + lr) * 8];
#pragma unroll
    for (int mi = 0; mi < 4; ++mi)
#pragma unroll
      for (int ni = 0; ni < 4; ++ni)
        acc[mi][ni] = __builtin_amdgcn_mfma_f32_16x16x32_bf16(
            af[mi], bfr[ni], acc[mi][ni], 0, 0, 0);
  };

  const int nt = K >> 5;
  stage(0, 0);
  stage(1, 32);
  stage(2, 64);
  for (int t = 0; t < nt; ++t) {
    if (t + 2 < nt)      asm volatile("s_waitcnt vmcnt(8)" ::: "memory");
    else if (t + 1 < nt) asm volatile("s_waitcnt vmcnt(4)" ::: "memory");
    else                 asm volatile("s_waitcnt vmcnt(0)" ::: "memory");
    __builtin_amdgcn_s_barrier();
    const int buf = t % 3;
    compute(buf);
    __builtin_amdgcn_s_barrier();
    if (t + 3 < nt) stage(buf, (long)(t + 3) << 5);
  }

  char* Cbase = (char*)Cv + ((long)zb * cB + (long)zs * cK) * (CBF ? 2 : 4);
#pragma unroll
  for (int mi = 0; mi < 4; ++mi)
#pragma unroll
    for (int ni = 0; ni < 4; ++ni) {
      int col = col0 + wc * 64 + ni * 16 + lr;
      float bv = bias ? bias[col] : 0.0f;
#pragma unroll
      for (int r = 0; r < 4; ++r) {
        int row = row0 + wr * 64 + mi * 16 + kb * 4 + r;
        float vv = (acc[mi][ni][r] + bv) * scale + sb;
        if (relu) vv = fmaxf(vv, 0.0f);
        if constexpr (CBF)
          ((us*)Cbase)[(long)row * ldc + col] = bf16o(vv);
        else
          ((float*)Cbase)[(long)row * ldc + col] = vv;
      }
    }
}

// ---------------- bf16 MFMA GEMM, B NOT transposed (K-major), reg-staged ----
__global__ __launch_bounds__(256) void gemm_nt_bb(
    const us* __restrict__ A, const us* __restrict__ Bm,
    us* __restrict__ C, int K, int lda, int ldb, int ldc,
    long aB, long bB, long cB)
{
  __shared__ us sA[4096];
  __shared__ us sB[4096];
  int rowT, colT;
  tile_map(rowT, colT);
  const int bz = blockIdx.z;
  const int row0 = rowT * 128, col0 = colT * 128;
  const us* Ap = A + (long)bz * aB + (long)row0 * lda;
  const us* Bp = Bm + (long)bz * bB + col0;

  const int lane = threadIdx.x & 63, wid = threadIdx.x >> 6;
  const int wr = wid >> 1, wc = wid & 1;
  const int lr = lane & 15, kb = lane >> 4;
  const int kq = threadIdx.x & 7, m0 = threadIdx.x >> 3;
  const int k8 = threadIdx.x >> 5, c4 = threadIdx.x & 31;

  f32x4 acc[4][4];
#pragma unroll
  for (int mi = 0; mi < 4; ++mi)
#pragma unroll
    for (int ni = 0; ni < 4; ++ni) {
      f32x4 z = {0.f, 0.f, 0.f, 0.f};
      acc[mi][ni] = z;
    }

  uint2 ra[4], rb[4];
#pragma unroll
  for (int i = 0; i < 4; ++i) {
    int m = m0 + 32 * i;
    ra[i] = *(const uint2*)(Ap + (long)m * lda + kq * 4);
    int kk = k8 + 8 * i;
    rb[i] = *(const uint2*)(Bp + (long)kk * ldb + c4 * 4);
  }

  for (int k0 = 0;;) {
#pragma unroll
    for (int i = 0; i < 4; ++i) {
      int m = m0 + 32 * i;
      int idx = swz(((kq >> 1) * 128 + m) * 8 + (kq & 1) * 4);
      *(uint2*)&sA[idx] = ra[i];
      int b0 = (i * 128 + c4 * 4) * 8 + k8;   // transpose at staging
      sB[swz(b0)]      = (us)(rb[i].x & 0xffffu);
      sB[swz(b0 + 8)]  = (us)(rb[i].x >> 16);
      sB[swz(b0 + 16)] = (us)(rb[i].y & 0xffffu);
      sB[swz(b0 + 24)] = (us)(rb[i].y >> 16);
    }
    __syncthreads();
    k0 += 32;
    if (k0 < K) {
#pragma unroll
      for (int i = 0; i < 4; ++i) {
        int m = m0 + 32 * i;
        ra[i] = *(const uint2*)(Ap + (long)m * lda + k0 + kq * 4);
        int kk = k8 + 8 * i;
        rb[i] = *(const uint2*)(Bp + (long)(k0 + kk) * ldb + c4 * 4);
      }
    }
    short8 af[4], bfr[4];
#pragma unroll
    for (int mi = 0; mi < 4; ++mi)
      af[mi] = *(const short8*)&sA[swz((kb * 128 + wr * 64 + mi * 16 + lr) * 8)];
#pragma unroll
    for (int ni = 0; ni < 4; ++ni)
      bfr[ni] = *(const short8*)&sB[swz((kb * 128 + wc * 64 + ni * 16 + lr) * 8)];
#pragma unroll
    for (int mi = 0; mi < 4; ++mi)
#pragma unroll
      for (int ni = 0; ni < 4; ++ni)
        acc[mi][ni] = __builtin_amdgcn_mfma_f32_16x16x32_bf16(
            af[mi], bfr[ni], acc[mi][ni], 0, 0, 0);
    __syncthreads();
    if (k0 >= K) break;
  }

  us* Cp = C + (long)bz * cB;
#pragma unroll
  for (int mi = 0; mi < 4; ++mi)
#pragma unroll
    for (int ni = 0; ni < 4; ++ni) {
      int col = col0 + wc * 64 + ni * 16 + lr;
#pragma unroll
      for (int r = 0; r < 4; ++r) {
        int row = row0 + wr * 64 + mi * 16 + kb * 4 + r;
        Cp[(long)row * ldc + col] = bf16o(acc[mi][ni][r]);
      }
    }
}

// ------ masked softmax over s from 4 split-K partials; fp32+bf16 out --------
// mem_bias[b] is constant per row -> softmax-invariant -> dropped exactly.
__global__ __launch_bounds__(256) void attn_softmax4(
    const float* __restrict__ wp, float* __restrict__ w,
    us* __restrict__ wbf, const int* __restrict__ mask)
{
  __shared__ float sh[4];
  const int blk = blockIdx.x;          // b*T + t
  const int b = blk / T_;
  const long base = (long)blk * S_;
  float* row = w + base;
  us* rowb = wbf + base;
  const int s0 = threadIdx.x, s1 = threadIdx.x + 256;
  const bool k0 = mask[s0 * B_ + b] != 0;
  const bool k1 = mask[s1 * B_ + b] != 0;
  float x0 = wp[base + s0] + wp[1048576 + base + s0]
           + wp[2097152 + base + s0] + wp[3145728 + base + s0];
  float x1 = wp[base + s1] + wp[1048576 + base + s1]
           + wp[2097152 + base + s1] + wp[3145728 + base + s1];
  x0 = k0 ? x0 : -INFINITY;
  x1 = k1 ? x1 : -INFINITY;
  float m = blkMax(fmaxf(x0, x1), sh);
  float e0 = k0 ? expf(x0 - m) : 0.0f;
  float e1 = k1 ? expf(x1 - m) : 0.0f;
  float sum = blkSum(e0 + e1, sh);
  float inv = sum > 0.0f ? 1.0f / sum : 0.0f;
  float p0 = e0 * inv, p1 = e1 * inv;
  row[s0] = p0; row[s1] = p1;
  rowb[s0] = bf16o(p0); rowb[s1] = bf16o(p1);
}

// ------- gates + h1 = LN(outs+attn); attn = pa + pb + ob (split merge) ------
__global__ __launch_bounds__(256) void gates_h1(
    const float* __restrict__ outs, const float* __restrict__ pa,
    const float* __restrict__ pb, const float* __restrict__ ob,
    const float* __restrict__ aln_g, const float* __restrict__ aln_b,
    const float* __restrict__ div_w, const float* __restrict__ div_b,
    us* __restrict__ h1, float* __restrict__ gen, float* __restrict__ cpy)
{
  __shared__ float sh[4];
  const long base = (long)blockIdx.x * E_;
  float a[4], o[4];
  float sa = 0.f, sa2 = 0.f, shh = 0.f, sh2 = 0.f;
#pragma unroll
  for (int i = 0; i < 4; ++i) {
    int e = threadIdx.x + 256 * i;
    a[i] = pa[base + e] + pb[base + e] + ob[e];
    o[i] = outs[base + e];
    sa += a[i]; sa2 += a[i] * a[i];
    float t = o[i] + a[i];
    shh += t; sh2 += t * t;
  }
  sa  = blkSum(sa, sh);
  sa2 = blkSum(sa2, sh);
  shh = blkSum(shh, sh);
  sh2 = blkSum(sh2, sh);
  const float ma = sa / E_, va = sa2 / E_ - ma * ma;
  const float mh = shh / E_, vh = sh2 / E_ - mh * mh;
  const float ra = rsqrtf(va + LN_EPSF), rh = rsqrtf(vh + LN_EPSF);

  float z0 = 0.f, z1 = 0.f;
#pragma unroll
  for (int i = 0; i < 4; ++i) {
    int e = threadIdx.x + 256 * i;
    float g = aln_g[e], bb = aln_b[e];
    float an = (a[i] - ma) * ra * g + bb;
    float hv = (o[i] + a[i] - mh) * rh * g + bb;
    h1[base + e] = bf16o(hv);
    z0 += o[i] * div_w[e]          + an * div_w[E_ + e];
    z1 += o[i] * div_w[2 * E_ + e] + an * div_w[3 * E_ + e];
  }
  z0 = blkSum(z0, sh);
  z1 = blkSum(z1, sh);
  if (threadIdx.x == 0) {
    z0 += div_b[0]; z1 += div_b[1];
    float mm = fmaxf(z0, z1);
    float e0 = expf(z0 - mm), e1 = expf(z1 - mm);
    float inv = 1.0f / (e0 + e1);
    gen[blockIdx.x] = e0 * inv;
    cpy[blockIdx.x] = e1 * inv;
  }
}

// ---------------- LN of (x1 + x2 + bias) -> bf16 (split-K fc2 merge) --------
__global__ __launch_bounds__(256) void ln2_bf16(
    const float* __restrict__ x1, const float* __restrict__ x2,
    const float* __restrict__ bias, const float* __restrict__ g,
    const float* __restrict__ b, us* __restrict__ o)
{
  __shared__ float sh[4];
  const long base = (long)blockIdx.x * E_;
  float v[4];
  float s = 0.f, s2 = 0.f;
#pragma unroll
  for (int i = 0; i < 4; ++i) {
    int e = threadIdx.x + 256 * i;
    v[i] = x1[base + e] + x2[base + e] + bias[e];
    s += v[i]; s2 += v[i] * v[i];
  }
  s  = blkSum(s, sh);
  s2 = blkSum(s2, sh);
  const float m = s / E_, var = s2 / E_ - m * m;
  const float r = rsqrtf(var + LN_EPSF);
#pragma unroll
  for (int i = 0; i < 4; ++i) {
    int e = threadIdx.x + 256 * i;
    o[base + e] = bf16o((v[i] - m) * r * g[e] + b[e]);
  }
}

// ---- FUSED final: softmax(V)*gen + scatter (LDS accum) + log, one pass -----
__global__ __launch_bounds__(1024) void vocab_final(
    float* __restrict__ out, const float* __restrict__ gen,
    const float* __restrict__ cpy, const float* __restrict__ w,
    const int* __restrict__ copy_seq)
{
  __shared__ float scat[32000];
  __shared__ float sh[16];
  const int r = blockIdx.x, b = r & 7, t = r >> 3;
  const int tid = threadIdx.x;
  const short8* row8 = (const short8*)((us*)out + (long)r * 64000 + 32000);
  float4* row4 = (float4*)(out + (long)r * V_);

  for (int i = tid; i < V_; i += 1024) scat[i] = 0.f;
  __syncthreads();
  if (tid < S_) {
    float contrib = cpy[r] * w[((long)b * T_ + t) * S_ + tid];
    atomicAdd(&scat[copy_seq[tid * B_ + b]], contrib);
  }

  float vals[32];
  float mx = -INFINITY;
#pragma unroll
  for (int i = 0; i < 4; ++i) {
    int f = tid + (i << 10);          // short8 index, < 4000
    if (f < 4000) {
      short8 v8 = row8[f];
#pragma unroll
      for (int j = 0; j < 8; ++j) {
        float x = bf2f((us)v8[j]);
        vals[i * 8 + j] = x;
        mx = fmaxf(mx, x);
      }
    } else {
#pragma unroll
      for (int j = 0; j < 8; ++j) vals[i * 8 + j] = -INFINITY;
    }
  }
  const float gmx = blkMax16(mx, sh);  // barriers also publish scat

  float s = 0.f;
#pragma unroll
  for (int i = 0; i < 32; ++i) {
    vals[i] = expf(vals[i] - gmx);     // exp(-inf)=0 for pad lanes
    s += vals[i];
  }
  s = blkSum16(s, sh);

  const float scale = gen[r] / s;
#pragma unroll
  for (int i = 0; i < 4; ++i) {
    int f = tid + (i << 10);
    if (f < 4000) {
      int e0 = f * 8;
#pragma unroll
      for (int h = 0; h < 2; ++h) {
        float4 p;
        int eb = e0 + h * 4;
        p.x = logf(vals[i * 8 + h * 4 + 0] * scale + scat[eb + 0] + 1e-12f);
        p.y = logf(vals[i * 8 + h * 4 + 1] * scale + scat[eb + 1] + 1e-12f);
        p.z = logf(vals[i * 8 + h * 4 + 2] * scale + scat[eb + 2] + 1e-12f);
        p.w = logf(vals[i * 8 + h * 4 + 3] * scale + scat[eb + 3] + 1e-12f);
        row4[(e0 >> 2) + h] = p;
      }
    }
  }
}

// ---------------- launch ----------------------------------------------------
extern "C" void kernel_launch(void* const* d_in, const int* in_sizes, int n_in,
                              void* d_out, int out_size, void* d_ws, size_t ws_size,
                              hipStream_t stream) {
  (void)in_sizes; (void)n_in; (void)out_size; (void)ws_size;
  const float* outs     = (const float*)d_in[0];
  const float* mem      = (const float*)d_in[1];
  const float* in_w     = (const float*)d_in[3];
  const float* in_b     = (const float*)d_in[4];
  const float* ow       = (const float*)d_in[5];
  const float* ob       = (const float*)d_in[6];
  const float* aln_g    = (const float*)d_in[7];
  const float* aln_b    = (const float*)d_in[8];
  const float* div_w    = (const float*)d_in[9];
  const float* div_b    = (const float*)d_in[10];
  const float* fc1_w    = (const float*)d_in[11];
  const float* fc1_b    = (const float*)d_in[12];
  const float* fc2_w    = (const float*)d_in[13];
  const float* fc2_b    = (const float*)d_in[14];
  const float* ffn_g    = (const float*)d_in[15];
  const float* ffn_b    = (const float*)d_in[16];
  const float* vocab_w  = (const float*)d_in[17];
  const int*   mask     = (const int*)d_in[18];
  const int*   copy_seq = (const int*)d_in[19];
  float* out = (float*)d_out;
  char*  wsb = (char*)d_ws;

  // ---- workspace layout (bytes). Region A [0, 65.536 MB) is overwritten by
  // vocab_bf after ln2; every sub-buffer inside it is dead by then. ----
  us* in_w_bf  = (us*)(wsb + 0);          // 6.29 MB   dead after kv
  us* ow_bf    = (us*)(wsb + 6291456);    // 2.10 MB   dead after out_proj
  us* fc1_bf   = (us*)(wsb + 8388608);    // 8.39 MB   dead after fc1
  float* h2b   = (float*)(wsb + 8388608); //           fc2 partial 1 (after fc1)
  us* fc2_bf   = (us*)(wsb + 16777216);   // 8.39 MB   dead after fc2
  us* outs_bf  = (us*)(wsb + 25165824);   // 4.19 MB   dead after q
  us* h1_bf    = outs_bf;                 //           gates -> fc1
  us* mem_bf   = (us*)(wsb + 29360128);   // 8.39 MB   dead after kv
  float* attn_a= (float*)(wsb + 29360128);//           out_proj partial 0; then h2a
  float* h2a   = attn_a;                  //           fc2 partial 0
  us* q_bf     = (us*)(wsb + 37748736);   // 4.19 MB   dead after scores
  us* kv_bf    = (us*)(wsb + 41943040);   // 16.8 MB   k | v interleaved, ldc 2048
  float* attn_b= (float*)(wsb + 41943040);//           out_proj partial 1 (kv dead)
  us* w_bf     = (us*)(wsb + 58720256);   // 2.10 MB   dead after ctx
  us* ctx_bf   = (us*)(wsb + 60817408);   // 4.19 MB   dead after out_proj
  us* vocab_bf = (us*)(wsb + 0);          // 65.54 MB  overlays region A
  // ---- Region B: live through the end ----
  float* w_    = (float*)(wsb + 65536000);// 4.19 MB
  us* h2_bf    = (us*)(wsb + 69730304);   // 4.19 MB
  float* gen   = (float*)(wsb + 73924608);
  float* cpy   = gen + 2048;              // total 73.94 MB
  us* mid_bf   = (us*)d_out;              // 16.8 MB, dead before logits
  float* wp    = (float*)d_out;           // scores partials (4 x 4 MB), pre-fc1
  us* logits   = (us*)d_out + 32000;      // bf16 logits: row r at r*64000+32000

  dim3 blk(256), blk5(512);
  // all weight + activation conversions in ONE dispatch (4.72M float4)
  cvt_all<<<dim3(18432), blk, 0, stream>>>(
      outs, outs_bf, mem, mem_bf, in_w, in_w_bf, ow, ow_bf,
      fc1_w, fc1_bf, fc2_w, fc2_bf);
  // q = (outs @ Wq^T + bq) * E^-0.5  -> bf16
  gemm_gl<1><<<dim3(16, 8), blk, 0, stream>>>(outs_bf, in_w_bf, in_b, nullptr, q_bf,
      1024, 1024, 1024, 1024, 1, 0, 0, 0, 0, 0, 0, 0.03125f, 0);
  // kv = mem @ [Wk;Wv]^T + [bk;bv]  -> bf16 (N=2048, interleaved ldc=2048)
  gemm_gl<1><<<dim3(32, 16), blk, 0, stream>>>(mem_bf, in_w_bf + E_ * E_, in_b + E_, nullptr, kv_bf,
      1024, 1024, 1024, 2048, 1, 0, 0, 0, 0, 0, 0, 1.0f, 0);
  // scores split-K=4: z = sl*8+b; partials wp[sl] in d_out (mem_bias dropped:
  // constant per row -> softmax-invariant)
  gemm_gl<0><<<dim3(2, 4, 32), blk, 0, stream>>>(q_bf, kv_bf, nullptr, nullptr, wp,
      256, B_ * E_, B_ * 2048, S_, 8, E_, 2048, (long)T_ * S_, 256, 256, 1048576,
      1.0f, 0);
  attn_softmax4<<<dim3(B_ * T_), blk, 0, stream>>>(wp, w_, w_bf, mask);
  // ctx = w @ v   (v K-major: k-row stride B_*2048, batch off 2048)
  gemm_nt_bb<<<dim3(2, 8, 8), blk, 0, stream>>>(w_bf, kv_bf + 1024, ctx_bf,
      512, S_, B_ * 2048, B_ * E_, (long)T_ * S_, 2048, E_);
  // out_proj split-K=2: partials attn_a/attn_b (bias folded into gates_h1)
  gemm_gl<0><<<dim3(16, 8, 2), blk, 0, stream>>>(ctx_bf, ow_bf, nullptr, nullptr, attn_a,
      512, 1024, 1024, 1024, 1, 0, 0, 0, 512, 512, (long)(attn_b - attn_a),
      1.0f, 0);
  gates_h1<<<dim3(2048), blk, 0, stream>>>(outs, attn_a, attn_b, ob,
      aln_g, aln_b, div_w, div_b, h1_bf, gen, cpy);
  // mid = relu(h1 @ fc1^T + b1) -> bf16 in d_out
  gemm_gl<1><<<dim3(16, 32), blk, 0, stream>>>(h1_bf, fc1_bf, fc1_b, nullptr, mid_bf,
      1024, 1024, 1024, 4096, 1, 0, 0, 0, 0, 0, 0, 1.0f, 1);
  // fc2 split-K=2: partials h2a / h2b
  gemm_gl<0><<<dim3(16, 8, 2), blk, 0, stream>>>(mid_bf, fc2_bf, nullptr, nullptr, h2a,
      2048, 4096, 4096, 1024, 1, 0, 0, 0, 2048, 2048, (long)(h2b - h2a),
      1.0f, 0);
  // h2 = LN(h2a + h2b + fc2_b) -> bf16
  ln2_bf16<<<dim3(2048), blk, 0, stream>>>(h2a, h2b, fc2_b, ffn_g, ffn_b, h2_bf);
  // vocab weights -> bf16 (region A is all dead now)
  cvt_bf16<<<dim3(32000), blk, 0, stream>>>(vocab_w, vocab_bf, 8192000);
  // logits (bf16) = h2 @ vocab^T -> overlaid in d_out (row r at r*64000+32000)
  gemm_8p32<1><<<dim3(8, 125), blk5, 0, stream>>>(h2_bf, vocab_bf, nullptr, logits,
      1024, 1024, 1024, 64000, 1.0f, 0);
  // fused final: softmax*gen + LDS-scatter + log, single pass over the row
  vocab_final<<<dim3(2048), dim3(1024), 0, stream>>>(out, gen, cpy, w_, copy_seq);
}

// Round 21
// 642.555 us; speedup vs baseline: 1.0225x; 1.0225x over previous
//
#include <hip/hip_runtime.h>
#include <math.h>

#define T_ 256
#define B_ 8
#define S_ 512
#define E_ 1024
#define FF_ 4096
#define V_ 32000
#define LN_EPSF 1e-5f

typedef __attribute__((ext_vector_type(8))) short short8;
typedef __attribute__((ext_vector_type(4))) float f32x4;
typedef unsigned short us;

// ---------------- block reduction helpers -----------------------------------
__device__ __forceinline__ float blkSum(float v, float* sh) {
#pragma unroll
  for (int o = 32; o > 0; o >>= 1) v += __shfl_down(v, o, 64);
  if ((threadIdx.x & 63) == 0) sh[threadIdx.x >> 6] = v;
  __syncthreads();
  float r = sh[0] + sh[1] + sh[2] + sh[3];
  __syncthreads();
  return r;
}
__device__ __forceinline__ float blkMax(float v, float* sh) {
#pragma unroll
  for (int o = 32; o > 0; o >>= 1) v = fmaxf(v, __shfl_down(v, o, 64));
  if ((threadIdx.x & 63) == 0) sh[threadIdx.x >> 6] = v;
  __syncthreads();
  float r = fmaxf(fmaxf(sh[0], sh[1]), fmaxf(sh[2], sh[3]));
  __syncthreads();
  return r;
}
__device__ __forceinline__ float blkSum16(float v, float* sh) {
#pragma unroll
  for (int o = 32; o > 0; o >>= 1) v += __shfl_down(v, o, 64);
  if ((threadIdx.x & 63) == 0) sh[threadIdx.x >> 6] = v;
  __syncthreads();
  float r = 0.f;
#pragma unroll
  for (int i = 0; i < 16; ++i) r += sh[i];
  __syncthreads();
  return r;
}
__device__ __forceinline__ float blkMax16(float v, float* sh) {
#pragma unroll
  for (int o = 32; o > 0; o >>= 1) v = fmaxf(v, __shfl_down(v, o, 64));
  if ((threadIdx.x & 63) == 0) sh[threadIdx.x >> 6] = v;
  __syncthreads();
  float r = -INFINITY;
#pragma unroll
  for (int i = 0; i < 16; ++i) r = fmaxf(r, sh[i]);
  __syncthreads();
  return r;
}

// ---------------- f32 -> bf16 via HW cvt_pk (RNE) ---------------------------
__device__ __forceinline__ unsigned pkbf(float a, float b) {
  unsigned r;
  asm("v_cvt_pk_bf16_f32 %0, %1, %2" : "=v"(r) : "v"(a), "v"(b));
  return r;
}
__device__ __forceinline__ us bf16o(float a) {
  return (us)(pkbf(a, a) & 0xffffu);
}
__device__ __forceinline__ float bf2f(us u) {
  return __uint_as_float(((unsigned)u) << 16);
}

// ---------------- async global->LDS, 16B per lane ---------------------------
__device__ __forceinline__ void gl16(const us* g, us* l) {
  __builtin_amdgcn_global_load_lds(
      (const __attribute__((address_space(1))) void*)g,
      (__attribute__((address_space(3))) void*)l, 16, 0, 0);
}

// LDS XOR swizzle for the reg-staged nt kernel only (store+read, same xor)
__device__ __forceinline__ int swz(int idx) {
  return idx ^ (((idx >> 10) & 3) << 4);
}

// bijective XCD swizzle (m204): row-tile fastest within each XCD chunk
__device__ __forceinline__ void tile_map(int& rowT, int& colT) {
  const unsigned nwg = gridDim.x * gridDim.y;
  const unsigned lin = blockIdx.y * gridDim.x + blockIdx.x;
  const unsigned nq = nwg >> 3, rr = nwg & 7;
  const unsigned xcd = lin & 7, idx = lin >> 3;
  const unsigned s =
      (xcd < rr ? xcd * (nq + 1) : rr * (nq + 1) + (xcd - rr) * nq) + idx;
  rowT = s % gridDim.x;
  colT = s / gridDim.x;
}

// ---------------- cvt: fp32 -> packed bf16 (single big buffer) --------------
__global__ __launch_bounds__(256) void cvt_bf16(
    const float* __restrict__ in, us* __restrict__ o, int n4)
{
  int i = blockIdx.x * 256 + threadIdx.x;
  if (i < n4) {
    float4 f = ((const float4*)in)[i];
    ((uint2*)o)[i] = make_uint2(pkbf(f.x, f.y), pkbf(f.z, f.w));
  }
}

// ---------------- merged cvt of 6 tensors in one dispatch -------------------
__global__ __launch_bounds__(256) void cvt_all(
    const float* __restrict__ s0, us* __restrict__ d0,   // outs    524288
    const float* __restrict__ s1, us* __restrict__ d1,   // mem    1048576
    const float* __restrict__ s2, us* __restrict__ d2,   // in_w    786432
    const float* __restrict__ s3, us* __restrict__ d3,   // ow      262144
    const float* __restrict__ s4, us* __restrict__ d4,   // fc1    1048576
    const float* __restrict__ s5, us* __restrict__ d5)   // fc2    1048576
{
  int j = blockIdx.x * 256 + threadIdx.x;
  const float* s; us* d;
  if (j < 524288) { s = s0; d = d0; }
  else { j -= 524288; if (j < 1048576) { s = s1; d = d1; }
  else { j -= 1048576; if (j < 786432) { s = s2; d = d2; }
  else { j -= 786432; if (j < 262144) { s = s3; d = d3; }
  else { j -= 262144; if (j < 1048576) { s = s4; d = d4; }
  else { j -= 1048576; if (j >= 1048576) return; s = s5; d = d5; } } } } }
  float4 f = ((const float4*)s)[j];
  ((uint2*)d)[j] = make_uint2(pkbf(f.x, f.y), pkbf(f.z, f.w));
}

// ======== 256x256-tile bf16 GEMM: BK=64, 2 buf, 4 phases (best measured) ====
template<int CBF>
__global__ __launch_bounds__(512) void gemm_8p(
    const us* __restrict__ A, const us* __restrict__ Bm,
    const float* __restrict__ bias, void* __restrict__ Cv,
    int K, int lda, int ldb, int ldc, float scale, int relu)
{
  __shared__ us sA[2][16384], sB[2][16384];   // 128 KB
  int rowT, colT;
  tile_map(rowT, colT);
  const int row0 = rowT * 256, col0 = colT * 256;
  const us* Ap = A + (long)row0 * lda;
  const us* Bp = Bm + (long)col0 * ldb;

  const int lane = threadIdx.x & 63, wid = threadIdx.x >> 6;  // 8 waves
  const int wr = wid >> 2, wc = wid & 3;                      // 2x4 wave grid
  const int lr = lane & 15, kb = lane >> 4;

  long asrc[4], bsrc[4];
  int dst[4];
#pragma unroll
  for (int i = 0; i < 4; ++i) {
    int c = wid * 4 + i;
    int kg = c & 7, rq = c >> 3;
    asrc[i] = (long)(rq * 64 + lane) * lda + kg * 8;
    bsrc[i] = (long)(rq * 64 + lane) * ldb + kg * 8;
    dst[i] = kg * 2048 + rq * 512;   // [kg][256][8]; HW adds lane*16B
  }

  f32x4 acc[8][4];
#pragma unroll
  for (int j = 0; j < 8; ++j)
#pragma unroll
    for (int ni = 0; ni < 4; ++ni) {
      f32x4 z = {0.f, 0.f, 0.f, 0.f};
      acc[j][ni] = z;
    }

  const int nt = K >> 6;
#pragma unroll
  for (int i = 0; i < 4; ++i) gl16(Bp + bsrc[i], &sB[0][dst[i]]);
#pragma unroll
  for (int i = 0; i < 4; ++i) gl16(Ap + asrc[i], &sA[0][dst[i]]);
  asm volatile("s_waitcnt vmcnt(0)" ::: "memory");
  __builtin_amdgcn_s_barrier();

  for (int t = 0; t < nt; ++t) {
    const int buf = t & 1, nbuf = buf ^ 1;
    const long kN = (long)(t + 1) << 6;
    const bool pf = (t + 1) < nt;
    short8 bfr[4], af[4];

    // ---- phase 0: B[ks0] + A[h0,ks0]; prefetch B-next ----
#pragma unroll
    for (int ni = 0; ni < 4; ++ni)
      bfr[ni] = *(const short8*)&sB[buf][kb * 2048 + (wc * 64 + ni * 16 + lr) * 8];
#pragma unroll
    for (int mi = 0; mi < 4; ++mi)
      af[mi] = *(const short8*)&sA[buf][kb * 2048 + (wr * 128 + mi * 16 + lr) * 8];
    if (pf) {
#pragma unroll
      for (int i = 0; i < 4; ++i) gl16(Bp + bsrc[i] + kN, &sB[nbuf][dst[i]]);
    }
    __builtin_amdgcn_s_barrier();
    asm volatile("s_waitcnt lgkmcnt(0)" ::: "memory");
    __builtin_amdgcn_sched_barrier(0);
    __builtin_amdgcn_s_setprio(1);
#pragma unroll
    for (int mi = 0; mi < 4; ++mi)
#pragma unroll
      for (int ni = 0; ni < 4; ++ni)
        acc[mi][ni] = __builtin_amdgcn_mfma_f32_16x16x32_bf16(
            af[mi], bfr[ni], acc[mi][ni], 0, 0, 0);
    __builtin_amdgcn_s_setprio(0);
    __builtin_amdgcn_s_barrier();

    // ---- phase 1: A[h1,ks0]; prefetch A-next ----
#pragma unroll
    for (int mi = 0; mi < 4; ++mi)
      af[mi] = *(const short8*)&sA[buf][kb * 2048 + (wr * 128 + 64 + mi * 16 + lr) * 8];
    if (pf) {
#pragma unroll
      for (int i = 0; i < 4; ++i) gl16(Ap + asrc[i] + kN, &sA[nbuf][dst[i]]);
    }
    __builtin_amdgcn_s_barrier();
    asm volatile("s_waitcnt lgkmcnt(0)" ::: "memory");
    __builtin_amdgcn_sched_barrier(0);
    __builtin_amdgcn_s_setprio(1);
#pragma unroll
    for (int mi = 0; mi < 4; ++mi)
#pragma unroll
      for (int ni = 0; ni < 4; ++ni)
        acc[4 + mi][ni] = __builtin_amdgcn_mfma_f32_16x16x32_bf16(
            af[mi], bfr[ni], acc[4 + mi][ni], 0, 0, 0);
    __builtin_amdgcn_s_setprio(0);
    __builtin_amdgcn_s_barrier();

    // ---- phase 2: B[ks1] + A[h0,ks1] ----
#pragma unroll
    for (int ni = 0; ni < 4; ++ni)
      bfr[ni] = *(const short8*)&sB[buf][(4 + kb) * 2048 + (wc * 64 + ni * 16 + lr) * 8];
#pragma unroll
    for (int mi = 0; mi < 4; ++mi)
      af[mi] = *(const short8*)&sA[buf][(4 + kb) * 2048 + (wr * 128 + mi * 16 + lr) * 8];
    __builtin_amdgcn_s_barrier();
    asm volatile("s_waitcnt lgkmcnt(0)" ::: "memory");
    __builtin_amdgcn_sched_barrier(0);
    __builtin_amdgcn_s_setprio(1);
#pragma unroll
    for (int mi = 0; mi < 4; ++mi)
#pragma unroll
      for (int ni = 0; ni < 4; ++ni)
        acc[mi][ni] = __builtin_amdgcn_mfma_f32_16x16x32_bf16(
            af[mi], bfr[ni], acc[mi][ni], 0, 0, 0);
    __builtin_amdgcn_s_setprio(0);
    __builtin_amdgcn_s_barrier();

    // ---- phase 3: A[h1,ks1]; closing barrier doubles as next-tile-ready ----
#pragma unroll
    for (int mi = 0; mi < 4; ++mi)
      af[mi] = *(const short8*)&sA[buf][(4 + kb) * 2048 + (wr * 128 + 64 + mi * 16 + lr) * 8];
    __builtin_amdgcn_s_barrier();
    asm volatile("s_waitcnt lgkmcnt(0)" ::: "memory");
    __builtin_amdgcn_sched_barrier(0);
    __builtin_amdgcn_s_setprio(1);
#pragma unroll
    for (int mi = 0; mi < 4; ++mi)
#pragma unroll
      for (int ni = 0; ni < 4; ++ni)
        acc[4 + mi][ni] = __builtin_amdgcn_mfma_f32_16x16x32_bf16(
            af[mi], bfr[ni], acc[4 + mi][ni], 0, 0, 0);
    __builtin_amdgcn_s_setprio(0);
    asm volatile("s_waitcnt vmcnt(0)" ::: "memory");   // next tile landed
    __builtin_amdgcn_s_barrier();
  }

  // epilogue: C/D layout col=lane&15, row=(lane>>4)*4+reg
#pragma unroll
  for (int j = 0; j < 8; ++j)
#pragma unroll
    for (int ni = 0; ni < 4; ++ni) {
      int col = col0 + wc * 64 + ni * 16 + lr;
      float bv = bias ? bias[col] : 0.0f;
#pragma unroll
      for (int r = 0; r < 4; ++r) {
        int row = row0 + wr * 128 + (j >> 2) * 64 + (j & 3) * 16 + kb * 4 + r;
        float vv = (acc[j][ni][r] + bv) * scale;
        if (relu) vv = fmaxf(vv, 0.0f);
        if constexpr (CBF)
          ((us*)Cv)[(long)row * ldc + col] = bf16o(vv);
        else
          ((float*)Cv)[(long)row * ldc + col] = vv;
      }
    }
}

// ---------------- 128x128 bf16 GEMM, gl_lds, BK=32, 3-buf counted vmcnt -----
// z decomposes as (zb = z % zdiv, zs = z / zdiv): batch offsets (aB,bB,cB)
// and split-K offsets (aK,bK,cK) in elements.
template<int CBF>
__global__ __launch_bounds__(256) void gemm_gl(
    const us* __restrict__ A, const us* __restrict__ Bm,
    const float* __restrict__ bias, const float* __restrict__ sbias,
    void* __restrict__ Cv, int K, int lda, int ldb, int ldc, int zdiv,
    long aB, long bB, long cB, long aK, long bK, long cK,
    float scale, int relu)
{
  __shared__ us sA[3][4096], sB[3][4096];   // 48 KB -> 3 blocks/CU
  int rowT, colT;
  tile_map(rowT, colT);
  const int bz = blockIdx.z;
  const int zb = bz % zdiv, zs = bz / zdiv;
  const int row0 = rowT * 128, col0 = colT * 128;
  const us* Ap = A + (long)zb * aB + (long)zs * aK + (long)row0 * lda;
  const us* Bp = Bm + (long)zb * bB + (long)zs * bK + (long)col0 * ldb;
  const float sb = sbias ? sbias[zb] : 0.0f;

  const int lane = threadIdx.x & 63, wid = threadIdx.x >> 6;
  const int wr = wid >> 1, wc = wid & 1;
  const int lr = lane & 15, kb = lane >> 4;

  const int r1 = threadIdx.x & 127, q1 = threadIdx.x >> 7;
  const long a1 = (long)r1 * lda + q1 * 8, a2 = a1 + 16;
  const long b1 = (long)r1 * ldb + q1 * 8, b2 = b1 + 16;
  const int dof1 = wid * 512, dof2 = 2048 + wid * 512;

  f32x4 acc[4][4];
#pragma unroll
  for (int mi = 0; mi < 4; ++mi)
#pragma unroll
    for (int ni = 0; ni < 4; ++ni) {
      f32x4 z = {0.f, 0.f, 0.f, 0.f};
      acc[mi][ni] = z;
    }

  auto stage = [&](int buf, long k0) {
    gl16(Ap + a1 + k0, &sA[buf][dof1]);
    gl16(Ap + a2 + k0, &sA[buf][dof2]);
    gl16(Bp + b1 + k0, &sB[buf][dof1]);
    gl16(Bp + b2 + k0, &sB[buf][dof2]);
  };
  auto compute = [&](int buf) {
    short8 af[4], bfr[4];
#pragma unroll
    for (int mi = 0; mi < 4; ++mi)
      af[mi] = *(const short8*)&sA[buf][kb * 1024 + (wr * 64 + mi * 16 + lr) * 8];
#pragma unroll
    for (int ni = 0; ni < 4; ++ni)
      bfr[ni] = *(const short8*)&sB[buf][kb * 1024 + (wc * 64 + ni * 16 + lr) * 8];
#pragma unroll
    for (int mi = 0; mi < 4; ++mi)
#pragma unroll
      for (int ni = 0; ni < 4; ++ni)
        acc[mi][ni] = __builtin_amdgcn_mfma_f32_16x16x32_bf16(
            af[mi], bfr[ni], acc[mi][ni], 0, 0, 0);
  };

  const int nt = K >> 5;
  stage(0, 0);
  stage(1, 32);
  stage(2, 64);
  for (int t = 0; t < nt; ++t) {
    if (t + 2 < nt)      asm volatile("s_waitcnt vmcnt(8)" ::: "memory");
    else if (t + 1 < nt) asm volatile("s_waitcnt vmcnt(4)" ::: "memory");
    else                 asm volatile("s_waitcnt vmcnt(0)" ::: "memory");
    __builtin_amdgcn_s_barrier();
    const int buf = t % 3;
    compute(buf);
    __builtin_amdgcn_s_barrier();
    if (t + 3 < nt) stage(buf, (long)(t + 3) << 5);
  }

  char* Cbase = (char*)Cv + ((long)zb * cB + (long)zs * cK) * (CBF ? 2 : 4);
#pragma unroll
  for (int mi = 0; mi < 4; ++mi)
#pragma unroll
    for (int ni = 0; ni < 4; ++ni) {
      int col = col0 + wc * 64 + ni * 16 + lr;
      float bv = bias ? bias[col] : 0.0f;
#pragma unroll
      for (int r = 0; r < 4; ++r) {
        int row = row0 + wr * 64 + mi * 16 + kb * 4 + r;
        float vv = (acc[mi][ni][r] + bv) * scale + sb;
        if (relu) vv = fmaxf(vv, 0.0f);
        if constexpr (CBF)
          ((us*)Cbase)[(long)row * ldc + col] = bf16o(vv);
        else
          ((float*)Cbase)[(long)row * ldc + col] = vv;
      }
    }
}

// ---------------- bf16 MFMA GEMM, B NOT transposed (K-major), reg-staged ----
__global__ __launch_bounds__(256) void gemm_nt_bb(
    const us* __restrict__ A, const us* __restrict__ Bm,
    us* __restrict__ C, int K, int lda, int ldb, int ldc,
    long aB, long bB, long cB)
{
  __shared__ us sA[4096];
  __shared__ us sB[4096];
  int rowT, colT;
  tile_map(rowT, colT);
  const int bz = blockIdx.z;
  const int row0 = rowT * 128, col0 = colT * 128;
  const us* Ap = A + (long)bz * aB + (long)row0 * lda;
  const us* Bp = Bm + (long)bz * bB + col0;

  const int lane = threadIdx.x & 63, wid = threadIdx.x >> 6;
  const int wr = wid >> 1, wc = wid & 1;
  const int lr = lane & 15, kb = lane >> 4;
  const int kq = threadIdx.x & 7, m0 = threadIdx.x >> 3;
  const int k8 = threadIdx.x >> 5, c4 = threadIdx.x & 31;

  f32x4 acc[4][4];
#pragma unroll
  for (int mi = 0; mi < 4; ++mi)
#pragma unroll
    for (int ni = 0; ni < 4; ++ni) {
      f32x4 z = {0.f, 0.f, 0.f, 0.f};
      acc[mi][ni] = z;
    }

  uint2 ra[4], rb[4];
#pragma unroll
  for (int i = 0; i < 4; ++i) {
    int m = m0 + 32 * i;
    ra[i] = *(const uint2*)(Ap + (long)m * lda + kq * 4);
    int kk = k8 + 8 * i;
    rb[i] = *(const uint2*)(Bp + (long)kk * ldb + c4 * 4);
  }

  for (int k0 = 0;;) {
#pragma unroll
    for (int i = 0; i < 4; ++i) {
      int m = m0 + 32 * i;
      int idx = swz(((kq >> 1) * 128 + m) * 8 + (kq & 1) * 4);
      *(uint2*)&sA[idx] = ra[i];
      int b0 = (i * 128 + c4 * 4) * 8 + k8;   // transpose at staging
      sB[swz(b0)]      = (us)(rb[i].x & 0xffffu);
      sB[swz(b0 + 8)]  = (us)(rb[i].x >> 16);
      sB[swz(b0 + 16)] = (us)(rb[i].y & 0xffffu);
      sB[swz(b0 + 24)] = (us)(rb[i].y >> 16);
    }
    __syncthreads();
    k0 += 32;
    if (k0 < K) {
#pragma unroll
      for (int i = 0; i < 4; ++i) {
        int m = m0 + 32 * i;
        ra[i] = *(const uint2*)(Ap + (long)m * lda + k0 + kq * 4);
        int kk = k8 + 8 * i;
        rb[i] = *(const uint2*)(Bp + (long)(k0 + kk) * ldb + c4 * 4);
      }
    }
    short8 af[4], bfr[4];
#pragma unroll
    for (int mi = 0; mi < 4; ++mi)
      af[mi] = *(const short8*)&sA[swz((kb * 128 + wr * 64 + mi * 16 + lr) * 8)];
#pragma unroll
    for (int ni = 0; ni < 4; ++ni)
      bfr[ni] = *(const short8*)&sB[swz((kb * 128 + wc * 64 + ni * 16 + lr) * 8)];
#pragma unroll
    for (int mi = 0; mi < 4; ++mi)
#pragma unroll
      for (int ni = 0; ni < 4; ++ni)
        acc[mi][ni] = __builtin_amdgcn_mfma_f32_16x16x32_bf16(
            af[mi], bfr[ni], acc[mi][ni], 0, 0, 0);
    __syncthreads();
    if (k0 >= K) break;
  }

  us* Cp = C + (long)bz * cB;
#pragma unroll
  for (int mi = 0; mi < 4; ++mi)
#pragma unroll
    for (int ni = 0; ni < 4; ++ni) {
      int col = col0 + wc * 64 + ni * 16 + lr;
#pragma unroll
      for (int r = 0; r < 4; ++r) {
        int row = row0 + wr * 64 + mi * 16 + kb * 4 + r;
        Cp[(long)row * ldc + col] = bf16o(acc[mi][ni][r]);
      }
    }
}

// ------ masked softmax over s from 4 split-K partials; bf16 out only --------
// mem_bias[b] is constant per row -> softmax-invariant -> dropped exactly.
__global__ __launch_bounds__(256) void attn_softmax4(
    const float* __restrict__ wp, us* __restrict__ wbf,
    const int* __restrict__ mask)
{
  __shared__ float sh[4];
  const int blk = blockIdx.x;          // b*T + t
  const int b = blk / T_;
  const long base = (long)blk * S_;
  us* rowb = wbf + base;
  const int s0 = threadIdx.x, s1 = threadIdx.x + 256;
  const bool k0 = mask[s0 * B_ + b] != 0;
  const bool k1 = mask[s1 * B_ + b] != 0;
  float x0 = wp[base + s0] + wp[1048576 + base + s0]
           + wp[2097152 + base + s0] + wp[3145728 + base + s0];
  float x1 = wp[base + s1] + wp[1048576 + base + s1]
           + wp[2097152 + base + s1] + wp[3145728 + base + s1];
  x0 = k0 ? x0 : -INFINITY;
  x1 = k1 ? x1 : -INFINITY;
  float m = blkMax(fmaxf(x0, x1), sh);
  float e0 = k0 ? expf(x0 - m) : 0.0f;
  float e1 = k1 ? expf(x1 - m) : 0.0f;
  float sum = blkSum(e0 + e1, sh);
  float inv = sum > 0.0f ? 1.0f / sum : 0.0f;
  rowb[s0] = bf16o(e0 * inv);
  rowb[s1] = bf16o(e1 * inv);
}

// ------- gates + h1 = LN(outs+attn); attn = pa + pb + ob (split merge) ------
__global__ __launch_bounds__(256) void gates_h1(
    const float* __restrict__ outs, const float* __restrict__ pa,
    const float* __restrict__ pb, const float* __restrict__ ob,
    const float* __restrict__ aln_g, const float* __restrict__ aln_b,
    const float* __restrict__ div_w, const float* __restrict__ div_b,
    us* __restrict__ h1, float* __restrict__ gen, float* __restrict__ cpy)
{
  __shared__ float sh[4];
  const long base = (long)blockIdx.x * E_;
  float a[4], o[4];
  float sa = 0.f, sa2 = 0.f, shh = 0.f, sh2 = 0.f;
#pragma unroll
  for (int i = 0; i < 4; ++i) {
    int e = threadIdx.x + 256 * i;
    a[i] = pa[base + e] + pb[base + e] + ob[e];
    o[i] = outs[base + e];
    sa += a[i]; sa2 += a[i] * a[i];
    float t = o[i] + a[i];
    shh += t; sh2 += t * t;
  }
  sa  = blkSum(sa, sh);
  sa2 = blkSum(sa2, sh);
  shh = blkSum(shh, sh);
  sh2 = blkSum(sh2, sh);
  const float ma = sa / E_, va = sa2 / E_ - ma * ma;
  const float mh = shh / E_, vh = sh2 / E_ - mh * mh;
  const float ra = rsqrtf(va + LN_EPSF), rh = rsqrtf(vh + LN_EPSF);

  float z0 = 0.f, z1 = 0.f;
#pragma unroll
  for (int i = 0; i < 4; ++i) {
    int e = threadIdx.x + 256 * i;
    float g = aln_g[e], bb = aln_b[e];
    float an = (a[i] - ma) * ra * g + bb;
    float hv = (o[i] + a[i] - mh) * rh * g + bb;
    h1[base + e] = bf16o(hv);
    z0 += o[i] * div_w[e]          + an * div_w[E_ + e];
    z1 += o[i] * div_w[2 * E_ + e] + an * div_w[3 * E_ + e];
  }
  z0 = blkSum(z0, sh);
  z1 = blkSum(z1, sh);
  if (threadIdx.x == 0) {
    z0 += div_b[0]; z1 += div_b[1];
    float mm = fmaxf(z0, z1);
    float e0 = expf(z0 - mm), e1 = expf(z1 - mm);
    float inv = 1.0f / (e0 + e1);
    gen[blockIdx.x] = e0 * inv;
    cpy[blockIdx.x] = e1 * inv;
  }
}

// ---------------- LN of (x1 + x2 + bias) -> bf16 (split-K fc2 merge) --------
__global__ __launch_bounds__(256) void ln2_bf16(
    const float* __restrict__ x1, const float* __restrict__ x2,
    const float* __restrict__ bias, const float* __restrict__ g,
    const float* __restrict__ b, us* __restrict__ o)
{
  __shared__ float sh[4];
  const long base = (long)blockIdx.x * E_;
  float v[4];
  float s = 0.f, s2 = 0.f;
#pragma unroll
  for (int i = 0; i < 4; ++i) {
    int e = threadIdx.x + 256 * i;
    v[i] = x1[base + e] + x2[base + e] + bias[e];
    s += v[i]; s2 += v[i] * v[i];
  }
  s  = blkSum(s, sh);
  s2 = blkSum(s2, sh);
  const float m = s / E_, var = s2 / E_ - m * m;
  const float r = rsqrtf(var + LN_EPSF);
#pragma unroll
  for (int i = 0; i < 4; ++i) {
    int e = threadIdx.x + 256 * i;
    o[base + e] = bf16o((v[i] - m) * r * g[e] + b[e]);
  }
}

// ---- FUSED final: softmax(V)*gen + scatter (LDS accum) + log, one pass -----
// out[r][e] = log(gen[r]*softmax(logits[r])[e] + scat[r][e] + 1e-12); scat
// accumulated in LDS from bf16 attention probs. bf16 logits for row r live at
// (us*)out + r*64000 + 32000; all reads complete before the first write.
__global__ __launch_bounds__(1024) void vocab_final(
    float* __restrict__ out, const float* __restrict__ gen,
    const float* __restrict__ cpy, const us* __restrict__ wbf,
    const int* __restrict__ copy_seq)
{
  __shared__ float scat[32000];
  __shared__ float sh[16];
  const int r = blockIdx.x, b = r & 7, t = r >> 3;
  const int tid = threadIdx.x;
  const short8* row8 = (const short8*)((us*)out + (long)r * 64000 + 32000);
  float4* row4 = (float4*)(out + (long)r * V_);

  for (int i = tid; i < V_; i += 1024) scat[i] = 0.f;
  __syncthreads();
  if (tid < S_) {
    float contrib = cpy[r] * bf2f(wbf[((long)b * T_ + t) * S_ + tid]);
    atomicAdd(&scat[copy_seq[tid * B_ + b]], contrib);
  }

  float vals[32];
  float mx = -INFINITY;
#pragma unroll
  for (int i = 0; i < 4; ++i) {
    int f = tid + (i << 10);          // short8 index, < 4000
    if (f < 4000) {
      short8 v8 = row8[f];
#pragma unroll
      for (int j = 0; j < 8; ++j) {
        float x = bf2f((us)v8[j]);
        vals[i * 8 + j] = x;
        mx = fmaxf(mx, x);
      }
    } else {
#pragma unroll
      for (int j = 0; j < 8; ++j) vals[i * 8 + j] = -INFINITY;
    }
  }
  const float gmx = blkMax16(mx, sh);  // barriers also publish scat

  float s = 0.f;
#pragma unroll
  for (int i = 0; i < 32; ++i) {
    vals[i] = expf(vals[i] - gmx);     // exp(-inf)=0 for pad lanes
    s += vals[i];
  }
  s = blkSum16(s, sh);

  const float scale = gen[r] / s;
#pragma unroll
  for (int i = 0; i < 4; ++i) {
    int f = tid + (i << 10);
    if (f < 4000) {
      int e0 = f * 8;
#pragma unroll
      for (int h = 0; h < 2; ++h) {
        float4 p;
        int eb = e0 + h * 4;
        p.x = logf(vals[i * 8 + h * 4 + 0] * scale + scat[eb + 0] + 1e-12f);
        p.y = logf(vals[i * 8 + h * 4 + 1] * scale + scat[eb + 1] + 1e-12f);
        p.z = logf(vals[i * 8 + h * 4 + 2] * scale + scat[eb + 2] + 1e-12f);
        p.w = logf(vals[i * 8 + h * 4 + 3] * scale + scat[eb + 3] + 1e-12f);
        row4[(e0 >> 2) + h] = p;
      }
    }
  }
}

// ---------------- launch ----------------------------------------------------
extern "C" void kernel_launch(void* const* d_in, const int* in_sizes, int n_in,
                              void* d_out, int out_size, void* d_ws, size_t ws_size,
                              hipStream_t stream) {
  (void)in_sizes; (void)n_in; (void)out_size; (void)ws_size;
  const float* outs     = (const float*)d_in[0];
  const float* mem      = (const float*)d_in[1];
  const float* in_w     = (const float*)d_in[3];
  const float* in_b     = (const float*)d_in[4];
  const float* ow       = (const float*)d_in[5];
  const float* ob       = (const float*)d_in[6];
  const float* aln_g    = (const float*)d_in[7];
  const float* aln_b    = (const float*)d_in[8];
  const float* div_w    = (const float*)d_in[9];
  const float* div_b    = (const float*)d_in[10];
  const float* fc1_w    = (const float*)d_in[11];
  const float* fc1_b    = (const float*)d_in[12];
  const float* fc2_w    = (const float*)d_in[13];
  const float* fc2_b    = (const float*)d_in[14];
  const float* ffn_g    = (const float*)d_in[15];
  const float* ffn_b    = (const float*)d_in[16];
  const float* vocab_w  = (const float*)d_in[17];
  const int*   mask     = (const int*)d_in[18];
  const int*   copy_seq = (const int*)d_in[19];
  float* out = (float*)d_out;
  char*  wsb = (char*)d_ws;

  // ---- workspace layout (bytes). Region A [0, 65.536 MB) is overwritten by
  // vocab_bf after ln2; every sub-buffer inside it is dead by then. ----
  us* in_w_bf  = (us*)(wsb + 0);          // 6.29 MB   dead after kv
  us* ow_bf    = (us*)(wsb + 6291456);    // 2.10 MB   dead after out_proj
  us* fc1_bf   = (us*)(wsb + 8388608);    // 8.39 MB   dead after fc1
  float* h2b   = (float*)(wsb + 8388608); //           fc2 partial 1 (after fc1)
  us* fc2_bf   = (us*)(wsb + 16777216);   // 8.39 MB   dead after fc2
  us* outs_bf  = (us*)(wsb + 25165824);   // 4.19 MB   dead after q
  us* h1_bf    = outs_bf;                 //           gates -> fc1
  us* mem_bf   = (us*)(wsb + 29360128);   // 8.39 MB   dead after kv
  float* attn_a= (float*)(wsb + 29360128);//           out_proj partial 0; then h2a
  float* h2a   = attn_a;                  //           fc2 partial 0
  us* q_bf     = (us*)(wsb + 37748736);   // 4.19 MB   dead after scores
  us* kv_bf    = (us*)(wsb + 41943040);   // 16.8 MB   k | v interleaved, ldc 2048
  float* attn_b= (float*)(wsb + 41943040);//           out_proj partial 1 (kv dead)
  us* ctx_bf   = (us*)(wsb + 60817408);   // 4.19 MB   dead after out_proj
  us* vocab_bf = (us*)(wsb + 0);          // 65.54 MB  overlays region A
  // ---- Region B: live through the end ----
  us* w_bf     = (us*)(wsb + 65536000);   // 2.10 MB   bf16 attention probs
  us* h2_bf    = (us*)(wsb + 69730304);   // 4.19 MB
  float* gen   = (float*)(wsb + 73924608);
  float* cpy   = gen + 2048;              // total 73.94 MB
  us* mid_bf   = (us*)d_out;              // 16.8 MB, dead before logits
  float* wp    = (float*)d_out;           // scores partials (4 x 4 MB), pre-fc1
  us* logits   = (us*)d_out + 32000;      // bf16 logits: row r at r*64000+32000

  dim3 blk(256), blk5(512);
  // all weight + activation conversions in ONE dispatch (4.72M float4)
  cvt_all<<<dim3(18432), blk, 0, stream>>>(
      outs, outs_bf, mem, mem_bf, in_w, in_w_bf, ow, ow_bf,
      fc1_w, fc1_bf, fc2_w, fc2_bf);
  // q = (outs @ Wq^T + bq) * E^-0.5  -> bf16
  gemm_gl<1><<<dim3(16, 8), blk, 0, stream>>>(outs_bf, in_w_bf, in_b, nullptr, q_bf,
      1024, 1024, 1024, 1024, 1, 0, 0, 0, 0, 0, 0, 0.03125f, 0);
  // kv = mem @ [Wk;Wv]^T + [bk;bv]  -> bf16 (N=2048, interleaved ldc=2048)
  gemm_gl<1><<<dim3(32, 16), blk, 0, stream>>>(mem_bf, in_w_bf + E_ * E_, in_b + E_, nullptr, kv_bf,
      1024, 1024, 1024, 2048, 1, 0, 0, 0, 0, 0, 0, 1.0f, 0);
  // scores split-K=4: z = sl*8+b; partials wp[sl] in d_out (mem_bias dropped:
  // constant per row -> softmax-invariant)
  gemm_gl<0><<<dim3(2, 4, 32), blk, 0, stream>>>(q_bf, kv_bf, nullptr, nullptr, wp,
      256, B_ * E_, B_ * 2048, S_, 8, E_, 2048, (long)T_ * S_, 256, 256, 1048576,
      1.0f, 0);
  attn_softmax4<<<dim3(B_ * T_), blk, 0, stream>>>(wp, w_bf, mask);
  // ctx = w @ v   (v K-major: k-row stride B_*2048, batch off 2048)
  gemm_nt_bb<<<dim3(2, 8, 8), blk, 0, stream>>>(w_bf, kv_bf + 1024, ctx_bf,
      512, S_, B_ * 2048, B_ * E_, (long)T_ * S_, 2048, E_);
  // out_proj split-K=2: partials attn_a/attn_b (bias folded into gates_h1)
  gemm_gl<0><<<dim3(16, 8, 2), blk, 0, stream>>>(ctx_bf, ow_bf, nullptr, nullptr, attn_a,
      512, 1024, 1024, 1024, 1, 0, 0, 0, 512, 512, (long)(attn_b - attn_a),
      1.0f, 0);
  gates_h1<<<dim3(2048), blk, 0, stream>>>(outs, attn_a, attn_b, ob,
      aln_g, aln_b, div_w, div_b, h1_bf, gen, cpy);
  // mid = relu(h1 @ fc1^T + b1) -> bf16 in d_out
  gemm_gl<1><<<dim3(16, 32), blk, 0, stream>>>(h1_bf, fc1_bf, fc1_b, nullptr, mid_bf,
      1024, 1024, 1024, 4096, 1, 0, 0, 0, 0, 0, 0, 1.0f, 1);
  // fc2 split-K=2: partials h2a / h2b
  gemm_gl<0><<<dim3(16, 8, 2), blk, 0, stream>>>(mid_bf, fc2_bf, nullptr, nullptr, h2a,
      2048, 4096, 4096, 1024, 1, 0, 0, 0, 2048, 2048, (long)(h2b - h2a),
      1.0f, 0);
  // h2 = LN(h2a + h2b + fc2_b) -> bf16
  ln2_bf16<<<dim3(2048), blk, 0, stream>>>(h2a, h2b, fc2_b, ffn_g, ffn_b, h2_bf);
  // vocab weights -> bf16 (region A is all dead now)
  cvt_bf16<<<dim3(32000), blk, 0, stream>>>(vocab_w, vocab_bf, 8192000);
  // logits (bf16) = h2 @ vocab^T -> overlaid in d_out (row r at r*64000+32000)
  gemm_8p<1><<<dim3(8, 125), blk5, 0, stream>>>(h2_bf, vocab_bf, nullptr, logits,
      1024, 1024, 1024, 64000, 1.0f, 0);
  // fused final: softmax*gen + LDS-scatter + log, single pass over the row
  vocab_final<<<dim3(2048), dim3(1024), 0, stream>>>(out, gen, cpy, w_bf, copy_seq);
}

// Round 22
// 641.444 us; speedup vs baseline: 1.0243x; 1.0017x over previous
//
#include <hip/hip_runtime.h>
#include <math.h>

#define T_ 256
#define B_ 8
#define S_ 512
#define E_ 1024
#define FF_ 4096
#define V_ 32000
#define LN_EPSF 1e-5f

typedef __attribute__((ext_vector_type(8))) short short8;
typedef __attribute__((ext_vector_type(4))) float f32x4;
typedef unsigned short us;

// ---------------- block reduction helpers -----------------------------------
__device__ __forceinline__ float blkSum(float v, float* sh) {
#pragma unroll
  for (int o = 32; o > 0; o >>= 1) v += __shfl_down(v, o, 64);
  if ((threadIdx.x & 63) == 0) sh[threadIdx.x >> 6] = v;
  __syncthreads();
  float r = sh[0] + sh[1] + sh[2] + sh[3];
  __syncthreads();
  return r;
}
__device__ __forceinline__ float blkMax(float v, float* sh) {
#pragma unroll
  for (int o = 32; o > 0; o >>= 1) v = fmaxf(v, __shfl_down(v, o, 64));
  if ((threadIdx.x & 63) == 0) sh[threadIdx.x >> 6] = v;
  __syncthreads();
  float r = fmaxf(fmaxf(sh[0], sh[1]), fmaxf(sh[2], sh[3]));
  __syncthreads();
  return r;
}
__device__ __forceinline__ float blkSum16(float v, float* sh) {
#pragma unroll
  for (int o = 32; o > 0; o >>= 1) v += __shfl_down(v, o, 64);
  if ((threadIdx.x & 63) == 0) sh[threadIdx.x >> 6] = v;
  __syncthreads();
  float r = 0.f;
#pragma unroll
  for (int i = 0; i < 16; ++i) r += sh[i];
  __syncthreads();
  return r;
}
__device__ __forceinline__ float blkMax16(float v, float* sh) {
#pragma unroll
  for (int o = 32; o > 0; o >>= 1) v = fmaxf(v, __shfl_down(v, o, 64));
  if ((threadIdx.x & 63) == 0) sh[threadIdx.x >> 6] = v;
  __syncthreads();
  float r = -INFINITY;
#pragma unroll
  for (int i = 0; i < 16; ++i) r = fmaxf(r, sh[i]);
  __syncthreads();
  return r;
}

// ---------------- f32 -> bf16 via HW cvt_pk (RNE) ---------------------------
__device__ __forceinline__ unsigned pkbf(float a, float b) {
  unsigned r;
  asm("v_cvt_pk_bf16_f32 %0, %1, %2" : "=v"(r) : "v"(a), "v"(b));
  return r;
}
__device__ __forceinline__ us bf16o(float a) {
  return (us)(pkbf(a, a) & 0xffffu);
}
__device__ __forceinline__ float bf2f(us u) {
  return __uint_as_float(((unsigned)u) << 16);
}

// ---------------- async global->LDS, 16B per lane ---------------------------
__device__ __forceinline__ void gl16(const us* g, us* l) {
  __builtin_amdgcn_global_load_lds(
      (const __attribute__((address_space(1))) void*)g,
      (__attribute__((address_space(3))) void*)l, 16, 0, 0);
}

// LDS XOR swizzle for the reg-staged nt kernel only (store+read, same xor)
__device__ __forceinline__ int swz(int idx) {
  return idx ^ (((idx >> 10) & 3) << 4);
}

// bijective XCD swizzle (m204): row-tile fastest within each XCD chunk
__device__ __forceinline__ void tile_map(int& rowT, int& colT) {
  const unsigned nwg = gridDim.x * gridDim.y;
  const unsigned lin = blockIdx.y * gridDim.x + blockIdx.x;
  const unsigned nq = nwg >> 3, rr = nwg & 7;
  const unsigned xcd = lin & 7, idx = lin >> 3;
  const unsigned s =
      (xcd < rr ? xcd * (nq + 1) : rr * (nq + 1) + (xcd - rr) * nq) + idx;
  rowT = s % gridDim.x;
  colT = s / gridDim.x;
}

// ---------------- cvt: fp32 -> packed bf16 (single big buffer) --------------
__global__ __launch_bounds__(256) void cvt_bf16(
    const float* __restrict__ in, us* __restrict__ o, int n4)
{
  int i = blockIdx.x * 256 + threadIdx.x;
  if (i < n4) {
    float4 f = ((const float4*)in)[i];
    ((uint2*)o)[i] = make_uint2(pkbf(f.x, f.y), pkbf(f.z, f.w));
  }
}

// ---------------- merged cvt of 6 tensors in one dispatch -------------------
__global__ __launch_bounds__(256) void cvt_all(
    const float* __restrict__ s0, us* __restrict__ d0,   // outs    524288
    const float* __restrict__ s1, us* __restrict__ d1,   // mem    1048576
    const float* __restrict__ s2, us* __restrict__ d2,   // in_w    786432
    const float* __restrict__ s3, us* __restrict__ d3,   // ow      262144
    const float* __restrict__ s4, us* __restrict__ d4,   // fc1    1048576
    const float* __restrict__ s5, us* __restrict__ d5)   // fc2    1048576
{
  int j = blockIdx.x * 256 + threadIdx.x;
  const float* s; us* d;
  if (j < 524288) { s = s0; d = d0; }
  else { j -= 524288; if (j < 1048576) { s = s1; d = d1; }
  else { j -= 1048576; if (j < 786432) { s = s2; d = d2; }
  else { j -= 786432; if (j < 262144) { s = s3; d = d3; }
  else { j -= 262144; if (j < 1048576) { s = s4; d = d4; }
  else { j -= 1048576; if (j >= 1048576) return; s = s5; d = d5; } } } } }
  float4 f = ((const float4*)s)[j];
  ((uint2*)d)[j] = make_uint2(pkbf(f.x, f.y), pkbf(f.z, f.w));
}

// ======== 256x256-tile bf16 GEMM: BK=64, 2 buf, 4 phases (best measured) ====
template<int CBF>
__global__ __launch_bounds__(512) void gemm_8p(
    const us* __restrict__ A, const us* __restrict__ Bm,
    const float* __restrict__ bias, void* __restrict__ Cv,
    int K, int lda, int ldb, int ldc, float scale, int relu)
{
  __shared__ us sA[2][16384], sB[2][16384];   // 128 KB
  int rowT, colT;
  tile_map(rowT, colT);
  const int row0 = rowT * 256, col0 = colT * 256;
  const us* Ap = A + (long)row0 * lda;
  const us* Bp = Bm + (long)col0 * ldb;

  const int lane = threadIdx.x & 63, wid = threadIdx.x >> 6;  // 8 waves
  const int wr = wid >> 2, wc = wid & 3;                      // 2x4 wave grid
  const int lr = lane & 15, kb = lane >> 4;

  long asrc[4], bsrc[4];
  int dst[4];
#pragma unroll
  for (int i = 0; i < 4; ++i) {
    int c = wid * 4 + i;
    int kg = c & 7, rq = c >> 3;
    asrc[i] = (long)(rq * 64 + lane) * lda + kg * 8;
    bsrc[i] = (long)(rq * 64 + lane) * ldb + kg * 8;
    dst[i] = kg * 2048 + rq * 512;   // [kg][256][8]; HW adds lane*16B
  }

  f32x4 acc[8][4];
#pragma unroll
  for (int j = 0; j < 8; ++j)
#pragma unroll
    for (int ni = 0; ni < 4; ++ni) {
      f32x4 z = {0.f, 0.f, 0.f, 0.f};
      acc[j][ni] = z;
    }

  const int nt = K >> 6;
#pragma unroll
  for (int i = 0; i < 4; ++i) gl16(Bp + bsrc[i], &sB[0][dst[i]]);
#pragma unroll
  for (int i = 0; i < 4; ++i) gl16(Ap + asrc[i], &sA[0][dst[i]]);
  asm volatile("s_waitcnt vmcnt(0)" ::: "memory");
  __builtin_amdgcn_s_barrier();

  for (int t = 0; t < nt; ++t) {
    const int buf = t & 1, nbuf = buf ^ 1;
    const long kN = (long)(t + 1) << 6;
    const bool pf = (t + 1) < nt;
    short8 bfr[4], af[4];

    // ---- phase 0: B[ks0] + A[h0,ks0]; prefetch B-next ----
#pragma unroll
    for (int ni = 0; ni < 4; ++ni)
      bfr[ni] = *(const short8*)&sB[buf][kb * 2048 + (wc * 64 + ni * 16 + lr) * 8];
#pragma unroll
    for (int mi = 0; mi < 4; ++mi)
      af[mi] = *(const short8*)&sA[buf][kb * 2048 + (wr * 128 + mi * 16 + lr) * 8];
    if (pf) {
#pragma unroll
      for (int i = 0; i < 4; ++i) gl16(Bp + bsrc[i] + kN, &sB[nbuf][dst[i]]);
    }
    __builtin_amdgcn_s_barrier();
    asm volatile("s_waitcnt lgkmcnt(0)" ::: "memory");
    __builtin_amdgcn_sched_barrier(0);
    __builtin_amdgcn_s_setprio(1);
#pragma unroll
    for (int mi = 0; mi < 4; ++mi)
#pragma unroll
      for (int ni = 0; ni < 4; ++ni)
        acc[mi][ni] = __builtin_amdgcn_mfma_f32_16x16x32_bf16(
            af[mi], bfr[ni], acc[mi][ni], 0, 0, 0);
    __builtin_amdgcn_s_setprio(0);
    __builtin_amdgcn_s_barrier();

    // ---- phase 1: A[h1,ks0]; prefetch A-next ----
#pragma unroll
    for (int mi = 0; mi < 4; ++mi)
      af[mi] = *(const short8*)&sA[buf][kb * 2048 + (wr * 128 + 64 + mi * 16 + lr) * 8];
    if (pf) {
#pragma unroll
      for (int i = 0; i < 4; ++i) gl16(Ap + asrc[i] + kN, &sA[nbuf][dst[i]]);
    }
    __builtin_amdgcn_s_barrier();
    asm volatile("s_waitcnt lgkmcnt(0)" ::: "memory");
    __builtin_amdgcn_sched_barrier(0);
    __builtin_amdgcn_s_setprio(1);
#pragma unroll
    for (int mi = 0; mi < 4; ++mi)
#pragma unroll
      for (int ni = 0; ni < 4; ++ni)
        acc[4 + mi][ni] = __builtin_amdgcn_mfma_f32_16x16x32_bf16(
            af[mi], bfr[ni], acc[4 + mi][ni], 0, 0, 0);
    __builtin_amdgcn_s_setprio(0);
    __builtin_amdgcn_s_barrier();

    // ---- phase 2: B[ks1] + A[h0,ks1] ----
#pragma unroll
    for (int ni = 0; ni < 4; ++ni)
      bfr[ni] = *(const short8*)&sB[buf][(4 + kb) * 2048 + (wc * 64 + ni * 16 + lr) * 8];
#pragma unroll
    for (int mi = 0; mi < 4; ++mi)
      af[mi] = *(const short8*)&sA[buf][(4 + kb) * 2048 + (wr * 128 + mi * 16 + lr) * 8];
    __builtin_amdgcn_s_barrier();
    asm volatile("s_waitcnt lgkmcnt(0)" ::: "memory");
    __builtin_amdgcn_sched_barrier(0);
    __builtin_amdgcn_s_setprio(1);
#pragma unroll
    for (int mi = 0; mi < 4; ++mi)
#pragma unroll
      for (int ni = 0; ni < 4; ++ni)
        acc[mi][ni] = __builtin_amdgcn_mfma_f32_16x16x32_bf16(
            af[mi], bfr[ni], acc[mi][ni], 0, 0, 0);
    __builtin_amdgcn_s_setprio(0);
    __builtin_amdgcn_s_barrier();

    // ---- phase 3: A[h1,ks1]; closing barrier doubles as next-tile-ready ----
#pragma unroll
    for (int mi = 0; mi < 4; ++mi)
      af[mi] = *(const short8*)&sA[buf][(4 + kb) * 2048 + (wr * 128 + 64 + mi * 16 + lr) * 8];
    __builtin_amdgcn_s_barrier();
    asm volatile("s_waitcnt lgkmcnt(0)" ::: "memory");
    __builtin_amdgcn_sched_barrier(0);
    __builtin_amdgcn_s_setprio(1);
#pragma unroll
    for (int mi = 0; mi < 4; ++mi)
#pragma unroll
      for (int ni = 0; ni < 4; ++ni)
        acc[4 + mi][ni] = __builtin_amdgcn_mfma_f32_16x16x32_bf16(
            af[mi], bfr[ni], acc[4 + mi][ni], 0, 0, 0);
    __builtin_amdgcn_s_setprio(0);
    asm volatile("s_waitcnt vmcnt(0)" ::: "memory");   // next tile landed
    __builtin_amdgcn_s_barrier();
  }

  // epilogue: C/D layout col=lane&15, row=(lane>>4)*4+reg
#pragma unroll
  for (int j = 0; j < 8; ++j)
#pragma unroll
    for (int ni = 0; ni < 4; ++ni) {
      int col = col0 + wc * 64 + ni * 16 + lr;
      float bv = bias ? bias[col] : 0.0f;
#pragma unroll
      for (int r = 0; r < 4; ++r) {
        int row = row0 + wr * 128 + (j >> 2) * 64 + (j & 3) * 16 + kb * 4 + r;
        float vv = (acc[j][ni][r] + bv) * scale;
        if (relu) vv = fmaxf(vv, 0.0f);
        if constexpr (CBF)
          ((us*)Cv)[(long)row * ldc + col] = bf16o(vv);
        else
          ((float*)Cv)[(long)row * ldc + col] = vv;
      }
    }
}

// ---------------- 128x128 bf16 GEMM, gl_lds, BK=32, 3-buf counted vmcnt -----
// z decomposes as (zb = z % zdiv, zs = z / zdiv): batch offsets (aB,bB,cB)
// and split-K offsets (aK,bK,cK) in elements.
template<int CBF>
__global__ __launch_bounds__(256) void gemm_gl(
    const us* __restrict__ A, const us* __restrict__ Bm,
    const float* __restrict__ bias, const float* __restrict__ sbias,
    void* __restrict__ Cv, int K, int lda, int ldb, int ldc, int zdiv,
    long aB, long bB, long cB, long aK, long bK, long cK,
    float scale, int relu)
{
  __shared__ us sA[3][4096], sB[3][4096];   // 48 KB -> 3 blocks/CU
  int rowT, colT;
  tile_map(rowT, colT);
  const int bz = blockIdx.z;
  const int zb = bz % zdiv, zs = bz / zdiv;
  const int row0 = rowT * 128, col0 = colT * 128;
  const us* Ap = A + (long)zb * aB + (long)zs * aK + (long)row0 * lda;
  const us* Bp = Bm + (long)zb * bB + (long)zs * bK + (long)col0 * ldb;
  const float sb = sbias ? sbias[zb] : 0.0f;

  const int lane = threadIdx.x & 63, wid = threadIdx.x >> 6;
  const int wr = wid >> 1, wc = wid & 1;
  const int lr = lane & 15, kb = lane >> 4;

  const int r1 = threadIdx.x & 127, q1 = threadIdx.x >> 7;
  const long a1 = (long)r1 * lda + q1 * 8, a2 = a1 + 16;
  const long b1 = (long)r1 * ldb + q1 * 8, b2 = b1 + 16;
  const int dof1 = wid * 512, dof2 = 2048 + wid * 512;

  f32x4 acc[4][4];
#pragma unroll
  for (int mi = 0; mi < 4; ++mi)
#pragma unroll
    for (int ni = 0; ni < 4; ++ni) {
      f32x4 z = {0.f, 0.f, 0.f, 0.f};
      acc[mi][ni] = z;
    }

  auto stage = [&](int buf, long k0) {
    gl16(Ap + a1 + k0, &sA[buf][dof1]);
    gl16(Ap + a2 + k0, &sA[buf][dof2]);
    gl16(Bp + b1 + k0, &sB[buf][dof1]);
    gl16(Bp + b2 + k0, &sB[buf][dof2]);
  };
  auto compute = [&](int buf) {
    short8 af[4], bfr[4];
#pragma unroll
    for (int mi = 0; mi < 4; ++mi)
      af[mi] = *(const short8*)&sA[buf][kb * 1024 + (wr * 64 + mi * 16 + lr) * 8];
#pragma unroll
    for (int ni = 0; ni < 4; ++ni)
      bfr[ni] = *(const short8*)&sB[buf][kb * 1024 + (wc * 64 + ni * 16 + lr) * 8];
#pragma unroll
    for (int mi = 0; mi < 4; ++mi)
#pragma unroll
      for (int ni = 0; ni < 4; ++ni)
        acc[mi][ni] = __builtin_amdgcn_mfma_f32_16x16x32_bf16(
            af[mi], bfr[ni], acc[mi][ni], 0, 0, 0);
  };

  const int nt = K >> 5;
  stage(0, 0);
  stage(1, 32);
  stage(2, 64);
  for (int t = 0; t < nt; ++t) {
    if (t + 2 < nt)      asm volatile("s_waitcnt vmcnt(8)" ::: "memory");
    else if (t + 1 < nt) asm volatile("s_waitcnt vmcnt(4)" ::: "memory");
    else                 asm volatile("s_waitcnt vmcnt(0)" ::: "memory");
    __builtin_amdgcn_s_barrier();
    const int buf = t % 3;
    compute(buf);
    __builtin_amdgcn_s_barrier();
    if (t + 3 < nt) stage(buf, (long)(t + 3) << 5);
  }

  char* Cbase = (char*)Cv + ((long)zb * cB + (long)zs * cK) * (CBF ? 2 : 4);
#pragma unroll
  for (int mi = 0; mi < 4; ++mi)
#pragma unroll
    for (int ni = 0; ni < 4; ++ni) {
      int col = col0 + wc * 64 + ni * 16 + lr;
      float bv = bias ? bias[col] : 0.0f;
#pragma unroll
      for (int r = 0; r < 4; ++r) {
        int row = row0 + wr * 64 + mi * 16 + kb * 4 + r;
        float vv = (acc[mi][ni][r] + bv) * scale + sb;
        if (relu) vv = fmaxf(vv, 0.0f);
        if constexpr (CBF)
          ((us*)Cbase)[(long)row * ldc + col] = bf16o(vv);
        else
          ((float*)Cbase)[(long)row * ldc + col] = vv;
      }
    }
}

// ---------------- bf16 MFMA GEMM, B NOT transposed (K-major), reg-staged ----
__global__ __launch_bounds__(256) void gemm_nt_bb(
    const us* __restrict__ A, const us* __restrict__ Bm,
    us* __restrict__ C, int K, int lda, int ldb, int ldc,
    long aB, long bB, long cB)
{
  __shared__ us sA[4096];
  __shared__ us sB[4096];
  int rowT, colT;
  tile_map(rowT, colT);
  const int bz = blockIdx.z;
  const int row0 = rowT * 128, col0 = colT * 128;
  const us* Ap = A + (long)bz * aB + (long)row0 * lda;
  const us* Bp = Bm + (long)bz * bB + col0;

  const int lane = threadIdx.x & 63, wid = threadIdx.x >> 6;
  const int wr = wid >> 1, wc = wid & 1;
  const int lr = lane & 15, kb = lane >> 4;
  const int kq = threadIdx.x & 7, m0 = threadIdx.x >> 3;
  const int k8 = threadIdx.x >> 5, c4 = threadIdx.x & 31;

  f32x4 acc[4][4];
#pragma unroll
  for (int mi = 0; mi < 4; ++mi)
#pragma unroll
    for (int ni = 0; ni < 4; ++ni) {
      f32x4 z = {0.f, 0.f, 0.f, 0.f};
      acc[mi][ni] = z;
    }

  uint2 ra[4], rb[4];
#pragma unroll
  for (int i = 0; i < 4; ++i) {
    int m = m0 + 32 * i;
    ra[i] = *(const uint2*)(Ap + (long)m * lda + kq * 4);
    int kk = k8 + 8 * i;
    rb[i] = *(const uint2*)(Bp + (long)kk * ldb + c4 * 4);
  }

  for (int k0 = 0;;) {
#pragma unroll
    for (int i = 0; i < 4; ++i) {
      int m = m0 + 32 * i;
      int idx = swz(((kq >> 1) * 128 + m) * 8 + (kq & 1) * 4);
      *(uint2*)&sA[idx] = ra[i];
      int b0 = (i * 128 + c4 * 4) * 8 + k8;   // transpose at staging
      sB[swz(b0)]      = (us)(rb[i].x & 0xffffu);
      sB[swz(b0 + 8)]  = (us)(rb[i].x >> 16);
      sB[swz(b0 + 16)] = (us)(rb[i].y & 0xffffu);
      sB[swz(b0 + 24)] = (us)(rb[i].y >> 16);
    }
    __syncthreads();
    k0 += 32;
    if (k0 < K) {
#pragma unroll
      for (int i = 0; i < 4; ++i) {
        int m = m0 + 32 * i;
        ra[i] = *(const uint2*)(Ap + (long)m * lda + k0 + kq * 4);
        int kk = k8 + 8 * i;
        rb[i] = *(const uint2*)(Bp + (long)(k0 + kk) * ldb + c4 * 4);
      }
    }
    short8 af[4], bfr[4];
#pragma unroll
    for (int mi = 0; mi < 4; ++mi)
      af[mi] = *(const short8*)&sA[swz((kb * 128 + wr * 64 + mi * 16 + lr) * 8)];
#pragma unroll
    for (int ni = 0; ni < 4; ++ni)
      bfr[ni] = *(const short8*)&sB[swz((kb * 128 + wc * 64 + ni * 16 + lr) * 8)];
#pragma unroll
    for (int mi = 0; mi < 4; ++mi)
#pragma unroll
      for (int ni = 0; ni < 4; ++ni)
        acc[mi][ni] = __builtin_amdgcn_mfma_f32_16x16x32_bf16(
            af[mi], bfr[ni], acc[mi][ni], 0, 0, 0);
    __syncthreads();
    if (k0 >= K) break;
  }

  us* Cp = C + (long)bz * cB;
#pragma unroll
  for (int mi = 0; mi < 4; ++mi)
#pragma unroll
    for (int ni = 0; ni < 4; ++ni) {
      int col = col0 + wc * 64 + ni * 16 + lr;
#pragma unroll
      for (int r = 0; r < 4; ++r) {
        int row = row0 + wr * 64 + mi * 16 + kb * 4 + r;
        Cp[(long)row * ldc + col] = bf16o(acc[mi][ni][r]);
      }
    }
}

// ------ masked softmax over s from 4 split-K partials; bf16 out only --------
// mem_bias[b] is constant per row -> softmax-invariant -> dropped exactly.
__global__ __launch_bounds__(256) void attn_softmax4(
    const float* __restrict__ wp, us* __restrict__ wbf,
    const int* __restrict__ mask)
{
  __shared__ float sh[4];
  const int blk = blockIdx.x;          // b*T + t
  const int b = blk / T_;
  const long base = (long)blk * S_;
  us* rowb = wbf + base;
  const int s0 = threadIdx.x, s1 = threadIdx.x + 256;
  const bool k0 = mask[s0 * B_ + b] != 0;
  const bool k1 = mask[s1 * B_ + b] != 0;
  float x0 = wp[base + s0] + wp[1048576 + base + s0]
           + wp[2097152 + base + s0] + wp[3145728 + base + s0];
  float x1 = wp[base + s1] + wp[1048576 + base + s1]
           + wp[2097152 + base + s1] + wp[3145728 + base + s1];
  x0 = k0 ? x0 : -INFINITY;
  x1 = k1 ? x1 : -INFINITY;
  float m = blkMax(fmaxf(x0, x1), sh);
  float e0 = k0 ? expf(x0 - m) : 0.0f;
  float e1 = k1 ? expf(x1 - m) : 0.0f;
  float sum = blkSum(e0 + e1, sh);
  float inv = sum > 0.0f ? 1.0f / sum : 0.0f;
  rowb[s0] = bf16o(e0 * inv);
  rowb[s1] = bf16o(e1 * inv);
}

// ------- gates + h1 = LN(outs+attn); attn = pa + pb + ob (split merge) ------
__global__ __launch_bounds__(256) void gates_h1(
    const float* __restrict__ outs, const float* __restrict__ pa,
    const float* __restrict__ pb, const float* __restrict__ ob,
    const float* __restrict__ aln_g, const float* __restrict__ aln_b,
    const float* __restrict__ div_w, const float* __restrict__ div_b,
    us* __restrict__ h1, float* __restrict__ gen, float* __restrict__ cpy)
{
  __shared__ float sh[4];
  const long base = (long)blockIdx.x * E_;
  float a[4], o[4];
  float sa = 0.f, sa2 = 0.f, shh = 0.f, sh2 = 0.f;
#pragma unroll
  for (int i = 0; i < 4; ++i) {
    int e = threadIdx.x + 256 * i;
    a[i] = pa[base + e] + pb[base + e] + ob[e];
    o[i] = outs[base + e];
    sa += a[i]; sa2 += a[i] * a[i];
    float t = o[i] + a[i];
    shh += t; sh2 += t * t;
  }
  sa  = blkSum(sa, sh);
  sa2 = blkSum(sa2, sh);
  shh = blkSum(shh, sh);
  sh2 = blkSum(sh2, sh);
  const float ma = sa / E_, va = sa2 / E_ - ma * ma;
  const float mh = shh / E_, vh = sh2 / E_ - mh * mh;
  const float ra = rsqrtf(va + LN_EPSF), rh = rsqrtf(vh + LN_EPSF);

  float z0 = 0.f, z1 = 0.f;
#pragma unroll
  for (int i = 0; i < 4; ++i) {
    int e = threadIdx.x + 256 * i;
    float g = aln_g[e], bb = aln_b[e];
    float an = (a[i] - ma) * ra * g + bb;
    float hv = (o[i] + a[i] - mh) * rh * g + bb;
    h1[base + e] = bf16o(hv);
    z0 += o[i] * div_w[e]          + an * div_w[E_ + e];
    z1 += o[i] * div_w[2 * E_ + e] + an * div_w[3 * E_ + e];
  }
  z0 = blkSum(z0, sh);
  z1 = blkSum(z1, sh);
  if (threadIdx.x == 0) {
    z0 += div_b[0]; z1 += div_b[1];
    float mm = fmaxf(z0, z1);
    float e0 = expf(z0 - mm), e1 = expf(z1 - mm);
    float inv = 1.0f / (e0 + e1);
    gen[blockIdx.x] = e0 * inv;
    cpy[blockIdx.x] = e1 * inv;
  }
}

// ---------------- LN of (x1 + x2 + bias) -> bf16 (split-K fc2 merge) --------
__global__ __launch_bounds__(256) void ln2_bf16(
    const float* __restrict__ x1, const float* __restrict__ x2,
    const float* __restrict__ bias, const float* __restrict__ g,
    const float* __restrict__ b, us* __restrict__ o)
{
  __shared__ float sh[4];
  const long base = (long)blockIdx.x * E_;
  float v[4];
  float s = 0.f, s2 = 0.f;
#pragma unroll
  for (int i = 0; i < 4; ++i) {
    int e = threadIdx.x + 256 * i;
    v[i] = x1[base + e] + x2[base + e] + bias[e];
    s += v[i]; s2 += v[i] * v[i];
  }
  s  = blkSum(s, sh);
  s2 = blkSum(s2, sh);
  const float m = s / E_, var = s2 / E_ - m * m;
  const float r = rsqrtf(var + LN_EPSF);
#pragma unroll
  for (int i = 0; i < 4; ++i) {
    int e = threadIdx.x + 256 * i;
    o[base + e] = bf16o((v[i] - m) * r * g[e] + b[e]);
  }
}

// ---- FUSED final: softmax(V)*gen + scatter (LDS accum) + log, one pass -----
// out[r][e] = log(gen[r]*softmax(logits[r])[e] + scat[r][e] + 1e-12); scat
// accumulated in LDS from bf16 attention probs. bf16 logits for row r live at
// (us*)out + r*64000 + 32000; all reads complete before the first write.
__global__ __launch_bounds__(1024) void vocab_final(
    float* __restrict__ out, const float* __restrict__ gen,
    const float* __restrict__ cpy, const us* __restrict__ wbf,
    const int* __restrict__ copy_seq)
{
  __shared__ float scat[32000];
  __shared__ float sh[16];
  const int r = blockIdx.x, b = r & 7, t = r >> 3;
  const int tid = threadIdx.x;
  const short8* row8 = (const short8*)((us*)out + (long)r * 64000 + 32000);
  float4* row4 = (float4*)(out + (long)r * V_);

  for (int i = tid; i < V_; i += 1024) scat[i] = 0.f;
  __syncthreads();
  if (tid < S_) {
    float contrib = cpy[r] * bf2f(wbf[((long)b * T_ + t) * S_ + tid]);
    atomicAdd(&scat[copy_seq[tid * B_ + b]], contrib);
  }

  float vals[32];
  float mx = -INFINITY;
#pragma unroll
  for (int i = 0; i < 4; ++i) {
    int f = tid + (i << 10);          // short8 index, < 4000
    if (f < 4000) {
      short8 v8 = row8[f];
#pragma unroll
      for (int j = 0; j < 8; ++j) {
        float x = bf2f((us)v8[j]);
        vals[i * 8 + j] = x;
        mx = fmaxf(mx, x);
      }
    } else {
#pragma unroll
      for (int j = 0; j < 8; ++j) vals[i * 8 + j] = -INFINITY;
    }
  }
  const float gmx = blkMax16(mx, sh);  // barriers also publish scat

  float s = 0.f;
#pragma unroll
  for (int i = 0; i < 32; ++i) {
    vals[i] = expf(vals[i] - gmx);     // exp(-inf)=0 for pad lanes
    s += vals[i];
  }
  s = blkSum16(s, sh);

  const float scale = gen[r] / s;
#pragma unroll
  for (int i = 0; i < 4; ++i) {
    int f = tid + (i << 10);
    if (f < 4000) {
      int e0 = f * 8;
#pragma unroll
      for (int h = 0; h < 2; ++h) {
        float4 p;
        int eb = e0 + h * 4;
        p.x = logf(vals[i * 8 + h * 4 + 0] * scale + scat[eb + 0] + 1e-12f);
        p.y = logf(vals[i * 8 + h * 4 + 1] * scale + scat[eb + 1] + 1e-12f);
        p.z = logf(vals[i * 8 + h * 4 + 2] * scale + scat[eb + 2] + 1e-12f);
        p.w = logf(vals[i * 8 + h * 4 + 3] * scale + scat[eb + 3] + 1e-12f);
        row4[(e0 >> 2) + h] = p;
      }
    }
  }
}

// ---------------- launch ----------------------------------------------------
extern "C" void kernel_launch(void* const* d_in, const int* in_sizes, int n_in,
                              void* d_out, int out_size, void* d_ws, size_t ws_size,
                              hipStream_t stream) {
  (void)in_sizes; (void)n_in; (void)out_size; (void)ws_size;
  const float* outs     = (const float*)d_in[0];
  const float* mem      = (const float*)d_in[1];
  const float* in_w     = (const float*)d_in[3];
  const float* in_b     = (const float*)d_in[4];
  const float* ow       = (const float*)d_in[5];
  const float* ob       = (const float*)d_in[6];
  const float* aln_g    = (const float*)d_in[7];
  const float* aln_b    = (const float*)d_in[8];
  const float* div_w    = (const float*)d_in[9];
  const float* div_b    = (const float*)d_in[10];
  const float* fc1_w    = (const float*)d_in[11];
  const float* fc1_b    = (const float*)d_in[12];
  const float* fc2_w    = (const float*)d_in[13];
  const float* fc2_b    = (const float*)d_in[14];
  const float* ffn_g    = (const float*)d_in[15];
  const float* ffn_b    = (const float*)d_in[16];
  const float* vocab_w  = (const float*)d_in[17];
  const int*   mask     = (const int*)d_in[18];
  const int*   copy_seq = (const int*)d_in[19];
  float* out = (float*)d_out;
  char*  wsb = (char*)d_ws;

  // ---- workspace layout (bytes). Region A [0, 65.536 MB) is overwritten by
  // vocab_bf after ln2; every sub-buffer inside it is dead by then. ----
  us* in_w_bf  = (us*)(wsb + 0);          // 6.29 MB   dead after kv
  us* ow_bf    = (us*)(wsb + 6291456);    // 2.10 MB   dead after out_proj
  us* fc1_bf   = (us*)(wsb + 8388608);    // 8.39 MB   dead after fc1
  float* h2b   = (float*)(wsb + 8388608); //           fc2 partial 1 (after fc1)
  us* fc2_bf   = (us*)(wsb + 16777216);   // 8.39 MB   dead after fc2
  us* outs_bf  = (us*)(wsb + 25165824);   // 4.19 MB   dead after q
  us* h1_bf    = outs_bf;                 //           gates -> fc1
  us* mem_bf   = (us*)(wsb + 29360128);   // 8.39 MB   dead after kv
  float* attn_a= (float*)(wsb + 29360128);//           out_proj partial 0; then h2a
  float* h2a   = attn_a;                  //           fc2 partial 0
  us* q_bf     = (us*)(wsb + 37748736);   // 4.19 MB   dead after scores
  us* kv_bf    = (us*)(wsb + 41943040);   // 16.8 MB   k | v interleaved, ldc 2048
  float* attn_b= (float*)(wsb + 41943040);//           out_proj partial 1 (kv dead)
  us* ctx_bf   = (us*)(wsb + 60817408);   // 4.19 MB   dead after out_proj
  us* vocab_bf = (us*)(wsb + 0);          // 65.54 MB  overlays region A
  // ---- Region B: live through the end ----
  us* w_bf     = (us*)(wsb + 65536000);   // 2.10 MB   bf16 attention probs
  us* h2_bf    = (us*)(wsb + 69730304);   // 4.19 MB
  float* gen   = (float*)(wsb + 73924608);
  float* cpy   = gen + 2048;              // total 73.94 MB
  us* mid_bf   = (us*)d_out;              // 16.8 MB, dead before logits
  float* wp    = (float*)d_out;           // scores partials (4 x 4 MB), pre-fc1
  us* logits   = (us*)d_out + 32000;      // bf16 logits: row r at r*64000+32000

  dim3 blk(256), blk5(512);
  // all weight + activation conversions in ONE dispatch (4.72M float4)
  cvt_all<<<dim3(18432), blk, 0, stream>>>(
      outs, outs_bf, mem, mem_bf, in_w, in_w_bf, ow, ow_bf,
      fc1_w, fc1_bf, fc2_w, fc2_bf);
  // q = (outs @ Wq^T + bq) * E^-0.5  -> bf16
  gemm_gl<1><<<dim3(16, 8), blk, 0, stream>>>(outs_bf, in_w_bf, in_b, nullptr, q_bf,
      1024, 1024, 1024, 1024, 1, 0, 0, 0, 0, 0, 0, 0.03125f, 0);
  // kv = mem @ [Wk;Wv]^T + [bk;bv]  -> bf16 (N=2048, interleaved ldc=2048)
  gemm_gl<1><<<dim3(32, 16), blk, 0, stream>>>(mem_bf, in_w_bf + E_ * E_, in_b + E_, nullptr, kv_bf,
      1024, 1024, 1024, 2048, 1, 0, 0, 0, 0, 0, 0, 1.0f, 0);
  // scores split-K=4: z = sl*8+b; partials wp[sl] in d_out (mem_bias dropped:
  // constant per row -> softmax-invariant)
  gemm_gl<0><<<dim3(2, 4, 32), blk, 0, stream>>>(q_bf, kv_bf, nullptr, nullptr, wp,
      256, B_ * E_, B_ * 2048, S_, 8, E_, 2048, (long)T_ * S_, 256, 256, 1048576,
      1.0f, 0);
  attn_softmax4<<<dim3(B_ * T_), blk, 0, stream>>>(wp, w_bf, mask);
  // ctx = w @ v   (v K-major: k-row stride B_*2048, batch off 2048)
  gemm_nt_bb<<<dim3(2, 8, 8), blk, 0, stream>>>(w_bf, kv_bf + 1024, ctx_bf,
      512, S_, B_ * 2048, B_ * E_, (long)T_ * S_, 2048, E_);
  // out_proj split-K=2: partials attn_a/attn_b (bias folded into gates_h1)
  gemm_gl<0><<<dim3(16, 8, 2), blk, 0, stream>>>(ctx_bf, ow_bf, nullptr, nullptr, attn_a,
      512, 1024, 1024, 1024, 1, 0, 0, 0, 512, 512, (long)(attn_b - attn_a),
      1.0f, 0);
  gates_h1<<<dim3(2048), blk, 0, stream>>>(outs, attn_a, attn_b, ob,
      aln_g, aln_b, div_w, div_b, h1_bf, gen, cpy);
  // mid = relu(h1 @ fc1^T + b1) -> bf16 in d_out
  gemm_gl<1><<<dim3(16, 32), blk, 0, stream>>>(h1_bf, fc1_bf, fc1_b, nullptr, mid_bf,
      1024, 1024, 1024, 4096, 1, 0, 0, 0, 0, 0, 0, 1.0f, 1);
  // fc2 split-K=2: partials h2a / h2b
  gemm_gl<0><<<dim3(16, 8, 2), blk, 0, stream>>>(mid_bf, fc2_bf, nullptr, nullptr, h2a,
      2048, 4096, 4096, 1024, 1, 0, 0, 0, 2048, 2048, (long)(h2b - h2a),
      1.0f, 0);
  // h2 = LN(h2a + h2b + fc2_b) -> bf16
  ln2_bf16<<<dim3(2048), blk, 0, stream>>>(h2a, h2b, fc2_b, ffn_g, ffn_b, h2_bf);
  // vocab weights -> bf16 (region A is all dead now)
  cvt_bf16<<<dim3(32000), blk, 0, stream>>>(vocab_w, vocab_bf, 8192000);
  // logits (bf16) = h2 @ vocab^T -> overlaid in d_out (row r at r*64000+32000)
  gemm_8p<1><<<dim3(8, 125), blk5, 0, stream>>>(h2_bf, vocab_bf, nullptr, logits,
      1024, 1024, 1024, 64000, 1.0f, 0);
  // fused final: softmax*gen + LDS-scatter + log, single pass over the row
  vocab_final<<<dim3(2048), dim3(1024), 0, stream>>>(out, gen, cpy, w_bf, copy_seq);
}